// Round 9
// baseline (187.281 us; speedup 1.0000x reference)
//
#include <hip/hip_runtime.h>

// Problem dims
#define Bb 8
#define Gg 512
#define Kk 64
#define Nn 1024
#define Mm 128
#define KM (Kk * Mm)      // 8192
#define GPB 16            // g per block in K1 z-pass
#define NCH 32            // Gg/GPB partial chunks

struct K1Args {
  const float *z, *hs_grid, *hs_key, *z1w;
  const float *wra_w, *wrh_w, *wla_w, *wlh_w, *kR_w;
  const float *wla_b, *wlh_b, *kR_b, *wra_b, *wrh_b;
  const float *wcl_w, *wcl_b, *wcR_w;
  const float *mapL_w, *mapL_b, *fin_w, *fin_b;
  float *att, *laNum, *laDen, *rdot, *Lk, *gbuf;
};

// ===========================================================================
// K1: [0,256) z-pass (barrier-free main loop, LDS-atomic ra accumulation)
//     [256,320) Lk chain | [320] g-vector block
// gbuf: gv1[0:128] gv2[128:256] gu[256:384] Cfull[384] fvecL[385:389]
// ===========================================================================
__global__ __launch_bounds__(1024, 4) void K1(K1Args a) {
  __shared__ __align__(16) float smem[6464];   // ~25.9 KB
  const int bid = blockIdx.x;
  const int t = threadIdx.x;

  if (bid < 256) {
    // ---------------- z-pass ----------------
    float* s_gw     = smem;            // 256: gw1[0:128] gw2[128:256]
    float* s_hsgrid = smem + 256;      // 2048
    float* s_ranum  = smem + 2304;     // 2048 (16 g x 128 m)
    float* s_raden  = smem + 4352;     // 2048
    float* s_red    = smem + 6400;     // 32
    float* s_fvecG  = smem + 2304;     // transient overlay (dead before zero-init)

    const int b = bid >> 5;
    const int gblk = bid & 31;
    const int lane_m = t & 31;
    const int m4 = lane_m << 2;
    const int kgrp = t >> 5;           // 0..31

    // stage hs_grid rows
    const float* hgb = a.hs_grid + ((size_t)b * Gg + gblk * GPB) * Mm;
    for (int idx = t; idx < GPB * Mm; idx += 1024) s_hsgrid[idx] = hgb[idx];
    // fvecG[m] = sum_l fin_w[l]*mapL_w[l, 132+m]
    if (t < 128) {
      float f = 0.f;
#pragma unroll
      for (int l = 0; l < 5; ++l) f += a.fin_w[l] * a.mapL_w[l * 260 + 132 + t];
      s_fvecG[t] = f;
    }
    __syncthreads();
    if (t < 256) {
      const int h = t & 127;
      const float* W = (t >> 7) ? a.wrh_w : a.wra_w;
      float g = 0.f;
      for (int mm = 0; mm < 128; ++mm) g += s_fvecG[mm] * W[(size_t)mm * Mm + h];
      s_gw[t] = g;
    }
    __syncthreads();
    for (int idx = t; idx < 2048; idx += 1024) { s_ranum[idx] = 0.f; s_raden[idx] = 0.f; }

    const int ofs0 = (kgrp * 2) * Mm + m4;
    const int ofs1 = ofs0 + Mm;
    const float4 hk0 = *reinterpret_cast<const float4*>(a.hs_key + (size_t)b * KM + ofs0);
    const float4 hk1 = *reinterpret_cast<const float4*>(a.hs_key + (size_t)b * KM + ofs1);
    const float zw0 = a.z1w[m4], zw1 = a.z1w[m4 + 1], zw2 = a.z1w[m4 + 2], zw3 = a.z1w[m4 + 3];

    float la_n[2][4], la_d[2][4];
#pragma unroll
    for (int i = 0; i < 2; ++i)
#pragma unroll
      for (int j = 0; j < 4; ++j) { la_n[i][j] = 0.f; la_d[i][j] = 0.f; }

    const float* zb = a.z + ((size_t)b * Gg + gblk * GPB) * (size_t)KM;
    float4 c0 = *reinterpret_cast<const float4*>(zb + ofs0);
    float4 c1 = *reinterpret_cast<const float4*>(zb + ofs1);

    __syncthreads();   // last barrier before the loop

    for (int gl = 0; gl < GPB; ++gl) {
      float4 n0 = c0, n1 = c1;
      if (gl < GPB - 1) {
        n0 = *reinterpret_cast<const float4*>(zb + (size_t)(gl + 1) * KM + ofs0);
        n1 = *reinterpret_cast<const float4*>(zb + (size_t)(gl + 1) * KM + ofs1);
      }
      const int g = gblk * GPB + gl;
      const float4 hg = *reinterpret_cast<const float4*>(s_hsgrid + gl * Mm + m4);
      float rn0 = 0, rn1 = 0, rn2 = 0, rn3 = 0, rd0 = 0, rd1 = 0, rd2 = 0, rd3 = 0;
#pragma unroll
      for (int i = 0; i < 2; ++i) {
        const float4 v = (i == 0) ? c0 : c1;
        const float4 hk = (i == 0) ? hk0 : hk1;
        const int k = kgrp * 2 + i;
        const float e0 = __expf(v.x), e1 = __expf(v.y), e2 = __expf(v.z), e3 = __expf(v.w);
        la_n[i][0] += e0 * hg.x; la_n[i][1] += e1 * hg.y; la_n[i][2] += e2 * hg.z; la_n[i][3] += e3 * hg.w;
        la_d[i][0] += e0;        la_d[i][1] += e1;        la_d[i][2] += e2;        la_d[i][3] += e3;
        rn0 += e0 * hk.x; rn1 += e1 * hk.y; rn2 += e2 * hk.z; rn3 += e3 * hk.w;
        rd0 += e0; rd1 += e1; rd2 += e2; rd3 += e3;
        float ap = v.x * zw0 + v.y * zw1 + v.z * zw2 + v.w * zw3;
        ap += __shfl_xor(ap, 16); ap += __shfl_xor(ap, 8); ap += __shfl_xor(ap, 4);
        ap += __shfl_xor(ap, 2);  ap += __shfl_xor(ap, 1);
        if (lane_m == 0) a.att[((size_t)b * Gg + g) * Kk + k] = ap;
      }
      // combine the wave's two kgrps, then LDS-atomic accumulate (no barrier!)
      rn0 += __shfl_xor(rn0, 32); rn1 += __shfl_xor(rn1, 32); rn2 += __shfl_xor(rn2, 32); rn3 += __shfl_xor(rn3, 32);
      rd0 += __shfl_xor(rd0, 32); rd1 += __shfl_xor(rd1, 32); rd2 += __shfl_xor(rd2, 32); rd3 += __shfl_xor(rd3, 32);
      if ((t & 63) < 32) {
        float* pn = s_ranum + gl * Mm + m4;
        float* pd = s_raden + gl * Mm + m4;
        atomicAdd(pn + 0, rn0); atomicAdd(pn + 1, rn1);
        atomicAdd(pn + 2, rn2); atomicAdd(pn + 3, rn3);
        atomicAdd(pd + 0, rd0); atomicAdd(pd + 1, rd1);
        atomicAdd(pd + 2, rd2); atomicAdd(pd + 3, rd3);
      }
      c0 = n0; c1 = n1;
    }

    // la partial stores (independent of the epilogue)
    const size_t base = ((size_t)(b * NCH + gblk)) * KM;
#pragma unroll
    for (int i = 0; i < 2; ++i) {
      const int k = kgrp * 2 + i;
      *reinterpret_cast<float4*>(a.laNum + base + k * Mm + m4) =
          make_float4(la_n[i][0], la_n[i][1], la_n[i][2], la_n[i][3]);
      *reinterpret_cast<float4*>(a.laDen + base + k * Mm + m4) =
          make_float4(la_d[i][0], la_d[i][1], la_d[i][2], la_d[i][3]);
    }

    __syncthreads();
    // epilogue: rdot[b,g] = gw1 . ra[g] + gw2 . hsgrid[g], 8 g per pass
#pragma unroll
    for (int p = 0; p < 2; ++p) {
      const int gl = p * 8 + (t >> 7);
      const int m = t & 127;
      const float rav = s_ranum[gl * Mm + m] / s_raden[gl * Mm + m];
      float val = s_gw[m] * rav + s_gw[128 + m] * s_hsgrid[gl * Mm + m];
      val += __shfl_xor(val, 32); val += __shfl_xor(val, 16); val += __shfl_xor(val, 8);
      val += __shfl_xor(val, 4);  val += __shfl_xor(val, 2);  val += __shfl_xor(val, 1);
      if ((t & 63) == 0) s_red[t >> 6] = val;    // slot = gl*2 + wave-half
      __syncthreads();
      if (t < 8) a.rdot[(size_t)b * Gg + gblk * GPB + p * 8 + t] = s_red[2 * t] + s_red[2 * t + 1];
      __syncthreads();
    }
  } else if (bid < 320) {
    // ---------------- Lk chain ----------------
    float* s_w  = smem;          // 32 x 132
    float* s_lh = smem + 4224;   // 8 x 132
    const int blk = bid - 256;
    const int b = blk >> 3, k8 = blk & 7;
    const int m = t & 127, kq = t >> 7;
    const int k = k8 * 8 + kq;
    float lh = 0.f;
    for (int hc = 0; hc < 4; ++hc) {
      for (int i = t; i < 4096; i += 1024) {
        const int mm = i >> 5, hh = i & 31;
        s_w[hh * 132 + mm] = a.wcl_w[(size_t)mm * Mm + hc * 32 + hh];
      }
      __syncthreads();
      const float* keyb = a.hs_key + ((size_t)b * Kk + k) * Mm + hc * 32;  // wave-uniform
      for (int hh = 0; hh < 32; ++hh) lh += keyb[hh] * s_w[hh * 132 + m];
      __syncthreads();
    }
    s_lh[kq * 132 + m] = lh + a.wcl_b[m];
    __syncthreads();
    float acc = 0.f;
    for (int mm = 0; mm < 128; ++mm)
      acc += s_lh[kq * 132 + mm] * a.wcR_w[(size_t)mm * Mm + m];
    a.Lk[((size_t)b * Kk + k) * Mm + m] = acc;
  } else {
    // ---------------- g-vector block ----------------
    float* s_fvec = smem;        // 260
    float* s_red  = smem + 260;  // 256
    if (t < 260) {
      float f = 0.f;
#pragma unroll
      for (int l = 0; l < 5; ++l) f += a.fin_w[l] * a.mapL_w[l * 260 + t];
      s_fvec[t] = f;
    }
    __syncthreads();
    const int h = t & 127, sel = t >> 7;
    if (sel < 3) {
      const float* W = (sel == 0) ? a.wla_w : (sel == 1) ? a.wlh_w : a.kR_w;
      float g = 0.f;
      for (int mm = 0; mm < 128; ++mm) g += s_fvec[mm] * W[(size_t)mm * Mm + h];
      a.gbuf[sel * 128 + h] = g;
    }
    if (t < 128) {
      s_red[t] = s_fvec[t] * (a.wla_b[t] + a.wlh_b[t] + a.kR_b[t]);
      s_red[128 + t] = s_fvec[132 + t] * (a.wra_b[t] + a.wrh_b[t]);
    }
    __syncthreads();
    if (t == 0) {
      float c1 = 0.f, c2 = 0.f;
      for (int i = 0; i < 128; ++i) { c1 += s_red[i]; c2 += s_red[128 + i]; }
      float C = a.fin_b[0];
#pragma unroll
      for (int l = 0; l < 5; ++l) C += a.fin_w[l] * a.mapL_b[l];
      // sA = sum att_l = G = 512 exactly; sR = sum att_r = K = 64 exactly
      a.gbuf[384] = C + 512.0f * c1 + 64.0f * c2;
#pragma unroll
      for (int e = 0; e < 4; ++e) a.gbuf[385 + e] = s_fvec[128 + e];
    }
  }
}

struct K2Args {
  const float *laNum, *laDen, *hs_key, *att, *rdot, *Lk, *hs_rec;
  const int *mask;
  const float *wRl, *gbuf;
  float *attlP, *attrPM, *attrPS, *attrPR, *pmT, *psT, *PSpT, *laDot, *keyDot;
};

// ===========================================================================
// K2: [0,64) laDot/keyDot | [64,128) att_l partials | [128,192) att_r
//     partials (b,gc) -> pm/ps/pr | [192,704) scores tiles -> pm/ps/PSp
// ===========================================================================
__global__ __launch_bounds__(256) void K2(K2Args a) {
  __shared__ __align__(16) float smem[4944];
  const int bid = blockIdx.x;
  const int t = threadIdx.x;

  if (bid < 64) {
    // ---- laDot[b,k] = gv1 . (num/den), keyDot[b,k] = gv2 . key[b,k,:]
    const int b = bid >> 3, k8 = bid & 7;
    const int m = t & 127, kh = t >> 7;
    const float g1 = a.gbuf[m], g2 = a.gbuf[128 + m];
    float* sl = smem;            // 8*132
    float* sk = smem + 1056;     // 8*132
#pragma unroll
    for (int i = 0; i < 4; ++i) {
      const int k = k8 * 8 + kh * 4 + i;
      const float* np = a.laNum + (size_t)b * NCH * KM + (size_t)k * Mm + m;
      const float* dp = a.laDen + (size_t)b * NCH * KM + (size_t)k * Mm + m;
      float num = 0.f, den = 0.f;
#pragma unroll 8
      for (int p = 0; p < NCH; ++p) { num += np[(size_t)p * KM]; den += dp[(size_t)p * KM]; }
      sl[(kh * 4 + i) * 132 + m] = g1 * (num / den);
      sk[(kh * 4 + i) * 132 + m] = g2 * a.hs_key[((size_t)b * Kk + k) * Mm + m];
    }
    __syncthreads();
    const int rid = t >> 5, l32 = t & 31;
    float s1 = sl[rid * 132 + l32] + sl[rid * 132 + l32 + 32] +
               sl[rid * 132 + l32 + 64] + sl[rid * 132 + l32 + 96];
    float s2 = sk[rid * 132 + l32] + sk[rid * 132 + l32 + 32] +
               sk[rid * 132 + l32 + 64] + sk[rid * 132 + l32 + 96];
#pragma unroll
    for (int off = 16; off; off >>= 1) { s1 += __shfl_xor(s1, off); s2 += __shfl_xor(s2, off); }
    if (l32 == 0) {
      a.laDot[b * Kk + k8 * 8 + rid] = s1;
      a.keyDot[b * Kk + k8 * 8 + rid] = s2;
    }
  } else if (bid < 128) {
    // ---- att_l partials ----
    const int blk = bid - 64;
    const int b = blk >> 3, p = blk & 7;
    const int w = t >> 6, lane = t & 63;
    float acc = 0.f;
    for (int j = 0; j < 16; ++j) {
      const int g = p * 64 + w * 16 + j;
      const float av = a.att[((size_t)b * Gg + g) * Kk + lane];
      float mx = av;
      for (int off = 32; off; off >>= 1) mx = fmaxf(mx, __shfl_xor(mx, off));
      const float e = __expf(av - mx);
      float s = e;
      for (int off = 32; off; off >>= 1) s += __shfl_xor(s, off);
      acc += e / s;
    }
    float* sred = smem;
    sred[w * 64 + lane] = acc;
    __syncthreads();
    if (t < 64) a.attlP[(b * 8 + p) * 64 + t] = sred[t] + sred[64 + t] + sred[128 + t] + sred[192 + t];
  } else if (bid < 192) {
    // ---- att_r online partials per (b, gc): pm, ps, pr (pr weights rdot) ----
    const int blk = bid - 128;
    const int b = blk >> 3, gc = blk & 7;
    const int k = t & 63, j4 = t >> 6;
    float m_ = -3.0e38f, s_ = 0.f, r_ = 0.f;
    for (int j = 0; j < 16; ++j) {
      const int g = gc * 64 + j4 * 16 + j;
      const float av = a.att[((size_t)b * Gg + g) * Kk + k];
      const float rv = a.rdot[(size_t)b * Gg + g];     // wave-uniform -> s_load
      if (av > m_) {
        const float sc = __expf(m_ - av);
        s_ = s_ * sc + 1.0f; r_ = r_ * sc + rv; m_ = av;
      } else {
        const float e = __expf(av - m_);
        s_ += e; r_ += e * rv;
      }
    }
    float* sm = smem;          // 256
    float* ss = smem + 256;    // 256
    float* sr = smem + 512;    // 256
    sm[j4 * 64 + k] = m_; ss[j4 * 64 + k] = s_; sr[j4 * 64 + k] = r_;
    __syncthreads();
    if (t < 64) {
      float M = sm[t];
      for (int q = 1; q < 4; ++q) M = fmaxf(M, sm[q * 64 + t]);
      float S = 0.f, R = 0.f;
      for (int q = 0; q < 4; ++q) {
        const float e = __expf(sm[q * 64 + t] - M);
        S += ss[q * 64 + t] * e; R += sr[q * 64 + t] * e;
      }
      const int o = (b * 8 + gc) * 64 + t;
      a.attrPM[o] = M; a.attrPS[o] = S; a.attrPR[o] = R;
    }
  } else {
    // ---- scores tile: pm/ps/PSp partials (scores stay in registers) ----
    const int vb = bid - 192;
    const int b = vb >> 6, ntile = vb & 63;
    const int n0 = ntile * 16;
    const int k = t & 63;
    const int hq = __builtin_amdgcn_readfirstlane(t >> 6);
    float* s_acc = smem;          // 4096
    float* s_m   = smem + 4096;   // 256
    float* s_s   = smem + 4352;   // 256
    float* s_p   = smem + 4608;   // 256
    float* s_ru4 = smem + 4864;   // 64
    float* s_ru  = smem + 4928;   // 16
    float rLk[32];
    {
      const float* Lp = a.Lk + ((size_t)b * Kk + k) * Mm + hq * 32;
#pragma unroll
      for (int j = 0; j < 8; ++j) {
        const float4 v = *reinterpret_cast<const float4*>(Lp + j * 4);
        rLk[j * 4 + 0] = v.x; rLk[j * 4 + 1] = v.y;
        rLk[j * 4 + 2] = v.z; rLk[j * 4 + 3] = v.w;
      }
    }
    float acc[16];
    const float* rb = a.hs_rec + ((size_t)b * Nn + n0) * Mm + hq * 32;   // wave-uniform
#pragma unroll
    for (int r = 0; r < 16; ++r) {
      const float* rp = rb + r * Mm;
      float s = 0.f;
#pragma unroll
      for (int j4 = 0; j4 < 8; ++j4) {
        const float4 rv = *reinterpret_cast<const float4*>(rp + j4 * 4);
        s += rv.x * rLk[j4 * 4] + rv.y * rLk[j4 * 4 + 1] +
             rv.z * rLk[j4 * 4 + 2] + rv.w * rLk[j4 * 4 + 3];
      }
      acc[r] = s;
    }
#pragma unroll
    for (int r = 0; r < 16; ++r) s_acc[(hq * 16 + r) * 64 + k] = acc[r];
    if (t < 64) {   // ru[n] = gu . rec[n,:] partials
      const int rt = t >> 2, hc = t & 3;
      const float* rp = a.hs_rec + ((size_t)b * Nn + n0 + rt) * Mm + hc * 32;
      const float* gu = a.gbuf + 256 + hc * 32;
      float s = 0.f;
#pragma unroll
      for (int j = 0; j < 32; ++j) s += gu[j] * rp[j];
      s_ru4[rt * 4 + hc] = s;
    }
    __syncthreads();
    if (t < 16) s_ru[t] = s_ru4[t * 4] + s_ru4[t * 4 + 1] + s_ru4[t * 4 + 2] + s_ru4[t * 4 + 3];
    __syncthreads();
    const float wv = a.wRl[0];
    const bool msk = (a.mask[b * Kk + k] == 0);
    float m = -3.0e38f, ssum = 0.f, psum = 0.f;
    const int hq4 = (t >> 6) * 4;
#pragma unroll
    for (int q = 0; q < 4; ++q) {
      const int r = hq4 + q;
      float v = s_acc[r * 64 + k] + s_acc[(16 + r) * 64 + k] +
                s_acc[(32 + r) * 64 + k] + s_acc[(48 + r) * 64 + k];
      v = msk ? -1e10f : wv * v;
      const float runow = s_ru[r];
      if (v > m) {
        const float sc = __expf(m - v);
        ssum = ssum * sc + 1.0f; psum = psum * sc + runow; m = v;
      } else {
        const float e = __expf(v - m);
        ssum += e; psum += e * runow;
      }
    }
    s_m[(t >> 6) * 64 + k] = m; s_s[(t >> 6) * 64 + k] = ssum; s_p[(t >> 6) * 64 + k] = psum;
    __syncthreads();
    if (t < 64) {
      float M = fmaxf(fmaxf(s_m[t], s_m[64 + t]), fmaxf(s_m[128 + t], s_m[192 + t]));
      float S = 0.f, P = 0.f;
#pragma unroll
      for (int q = 0; q < 4; ++q) {
        const float e = __expf(s_m[q * 64 + t] - M);
        S += s_s[q * 64 + t] * e; P += s_p[q * 64 + t] * e;
      }
      const size_t o = ((size_t)b * 64 + ntile) * 64 + t;
      a.pmT[o] = M; a.psT[o] = S; a.PSpT[o] = P;
    }
  }
}

// ===========================================================================
// K3: per-b finale (8 blocks x 64 threads): scalar assembly
// ===========================================================================
__global__ __launch_bounds__(64) void K3(
    const float* __restrict__ attlP, const float* __restrict__ pmT,
    const float* __restrict__ psT, const float* __restrict__ PSpT,
    const float* __restrict__ attrPM, const float* __restrict__ attrPS,
    const float* __restrict__ attrPR,
    const float* __restrict__ laDot, const float* __restrict__ keyDot,
    const float* __restrict__ gbuf, const float* __restrict__ lig_rep,
    float* __restrict__ out)
{
  const int b = blockIdx.x, t = threadIdx.x;   // t = k
  float attl = 0.f;
#pragma unroll
  for (int p = 0; p < 8; ++p) attl += attlP[(b * 8 + p) * 64 + t];
  // combine scores-softmax partials over 64 n-tiles
  float M = -3.0e38f, S = 0.f, P = 0.f;
  for (int nt = 0; nt < 64; ++nt) {
    const size_t o = ((size_t)b * 64 + nt) * 64 + t;
    const float pm_ = pmT[o], ps_ = psT[o], pp = PSpT[o];
    if (pm_ > M) {
      const float sc = __expf(M - pm_);
      S = S * sc + ps_; P = P * sc + pp; M = pm_;
    } else {
      const float e = __expf(pm_ - M);
      S += ps_ * e; P += pp * e;
    }
  }
  // combine att_r partials over 8 g-chunks -> grid_k = R/S
  float Mr = -3.0e38f, Sr = 0.f, Rr = 0.f;
  for (int p = 0; p < 8; ++p) {
    const int o = (b * 8 + p) * 64 + t;
    const float pm_ = attrPM[o], ps_ = attrPS[o], pr_ = attrPR[o];
    if (pm_ > Mr) {
      const float sc = __expf(Mr - pm_);
      Sr = Sr * sc + ps_; Rr = Rr * sc + pr_; Mr = pm_;
    } else {
      const float e = __expf(pm_ - Mr);
      Sr += ps_ * e; Rr += pr_ * e;
    }
  }
  float val = attl * (laDot[b * 64 + t] + keyDot[b * 64 + t] + P / S) + Rr / Sr;
#pragma unroll
  for (int off = 32; off; off >>= 1) val += __shfl_xor(val, off);
  if (t == 0) {
    float o = val + gbuf[384];
#pragma unroll
    for (int e = 0; e < 4; ++e) o += gbuf[385 + e] * lig_rep[b * 4 + e];
    out[b] = o;
  }
}

// ---------------------------------------------------------------------------
extern "C" void kernel_launch(void* const* d_in, const int* in_sizes, int n_in,
                              void* d_out, int out_size, void* d_ws, size_t ws_size,
                              hipStream_t stream) {
  float* w = (float*)d_ws;
  float* gbuf  = w;                       // 512
  float* att   = gbuf + 512;              // 262144
  float* laNum = att + Bb * Gg * Kk;      // 2097152
  float* laDen = laNum + Bb * NCH * KM;   // 2097152
  float* rdot  = laDen + Bb * NCH * KM;   // 4096
  float* Lk    = rdot + Bb * Gg;          // 65536
  float* attlP = Lk + Bb * Kk * Mm;       // 4096
  float* pmT   = attlP + Bb * 8 * 64;     // 32768
  float* psT   = pmT + Bb * 64 * 64;      // 32768
  float* PSpT  = psT + Bb * 64 * 64;      // 32768
  float* laDot = PSpT + Bb * 64 * 64;     // 512
  float* keyDot = laDot + Bb * Kk;        // 512
  float* attrPM = keyDot + Bb * Kk;       // 512
  float* attrPS = attrPM + Bb * 8 * 64;   // 512
  float* attrPR = attrPS + Bb * 8 * 64;   // 512

  K1Args a1;
  a1.z = (const float*)d_in[0];
  a1.hs_grid = (const float*)d_in[1];
  a1.hs_key = (const float*)d_in[2];
  a1.z1w = (const float*)d_in[15];
  a1.wra_w = (const float*)d_in[7];  a1.wra_b = (const float*)d_in[8];
  a1.wrh_w = (const float*)d_in[9];  a1.wrh_b = (const float*)d_in[10];
  a1.wla_w = (const float*)d_in[11]; a1.wla_b = (const float*)d_in[12];
  a1.wlh_w = (const float*)d_in[13]; a1.wlh_b = (const float*)d_in[14];
  a1.wcl_w = (const float*)d_in[19]; a1.wcl_b = (const float*)d_in[20];
  a1.wcR_w = (const float*)d_in[17];
  a1.kR_w  = (const float*)d_in[21]; a1.kR_b = (const float*)d_in[22];
  a1.mapL_w = (const float*)d_in[23]; a1.mapL_b = (const float*)d_in[24];
  a1.fin_w = (const float*)d_in[25]; a1.fin_b = (const float*)d_in[26];
  a1.att = att; a1.laNum = laNum; a1.laDen = laDen;
  a1.rdot = rdot; a1.Lk = Lk; a1.gbuf = gbuf;

  K2Args a2;
  a2.laNum = laNum; a2.laDen = laDen;
  a2.hs_key = (const float*)d_in[2];
  a2.att = att; a2.rdot = rdot; a2.Lk = Lk;
  a2.hs_rec = (const float*)d_in[4];
  a2.mask = (const int*)d_in[6];
  a2.wRl = (const float*)d_in[5];
  a2.gbuf = gbuf;
  a2.attlP = attlP;
  a2.attrPM = attrPM; a2.attrPS = attrPS; a2.attrPR = attrPR;
  a2.pmT = pmT; a2.psT = psT; a2.PSpT = PSpT;
  a2.laDot = laDot; a2.keyDot = keyDot;

  K1<<<321, 1024, 0, stream>>>(a1);
  K2<<<704, 256, 0, stream>>>(a2);
  K3<<<Bb, 64, 0, stream>>>(attlP, pmT, psT, PSpT, attrPM, attrPS, attrPR,
                            laDot, keyDot, gbuf, (const float*)d_in[3],
                            (float*)d_out);
}

// Round 10
// 120.233 us; speedup vs baseline: 1.5577x; 1.5577x over previous
//
#include <hip/hip_runtime.h>

// Problem dims
#define Bb 8
#define Gg 512
#define Kk 64
#define Nn 1024
#define Mm 128
#define KM 8192           // Kk*Mm
#define GPB 8             // g per z-block
#define NCH 64            // Gg/GPB partial chunks

struct K1Args {
  const float *z, *hs_grid, *hs_key, *z1w;
  const float *wra_w, *wrh_w, *wla_w, *wlh_w, *kR_w;
  const float *wla_b, *wlh_b, *kR_b, *wra_b, *wrh_b;
  const float *wcl_w, *wcl_b, *wcR_w;
  const float *mapL_w, *mapL_b, *fin_w, *fin_b;
  float *att, *laNum, *laDen, *raNum, *raDen, *Lk, *gbuf;
};

// ===========================================================================
// K1 (512 threads, >=2 blocks/CU):
//  [0,512)   z-pass: att, la partials, raw ra num/den sums  (pure streaming)
//  [512,576) Lk chain
//  [576]     g-vector block
// gbuf: gv1[0:128] gv2[128:256] gu[256:384] gw1[384:512] gw2[512:640]
//       Cfull[640] fvecL[641:645]
// ===========================================================================
__global__ __launch_bounds__(512, 4) void K1(K1Args a) {
  __shared__ __align__(16) float smem[5376];   // 21.5 KB
  const int bid = blockIdx.x;
  const int t = threadIdx.x;

  if (bid < 512) {
    // ---------------- z-pass ----------------
    float* s_hsgrid = smem;          // 1024
    float* s_rn     = smem + 1024;   // 2 x 1024 (double buffered)
    float* s_rd     = smem + 3072;   // 2 x 1024

    const int b = bid >> 6;
    const int gblk = bid & 63;
    const int m4 = (t & 31) << 2;
    const int kgrp = (t >> 5) & 15;  // 0..15
    const int wv = t >> 6;           // 0..7

    const float* hgb = a.hs_grid + ((size_t)b * Gg + gblk * GPB) * Mm;
    for (int idx = t; idx < GPB * Mm; idx += 512) s_hsgrid[idx] = hgb[idx];

    int krow[4];
    krow[0] = 2 * kgrp;      krow[1] = 2 * kgrp + 1;
    krow[2] = 2 * kgrp + 32; krow[3] = 2 * kgrp + 33;
    float4 hk[4];
#pragma unroll
    for (int q = 0; q < 4; ++q)
      hk[q] = *reinterpret_cast<const float4*>(a.hs_key + (size_t)b * KM + krow[q] * Mm + m4);
    const float zw0 = a.z1w[m4], zw1 = a.z1w[m4 + 1], zw2 = a.z1w[m4 + 2], zw3 = a.z1w[m4 + 3];

    float la_n[4][4], la_d[4][4];
#pragma unroll
    for (int q = 0; q < 4; ++q)
#pragma unroll
      for (int j = 0; j < 4; ++j) { la_n[q][j] = 0.f; la_d[q][j] = 0.f; }

    const float* zb = a.z + ((size_t)b * Gg + gblk * GPB) * (size_t)KM;
    float4 c[4];
#pragma unroll
    for (int q = 0; q < 4; ++q)
      c[q] = *reinterpret_cast<const float4*>(zb + krow[q] * Mm + m4);

    __syncthreads();

    for (int gl = 0; gl < GPB; ++gl) {
      float4 n[4];
#pragma unroll
      for (int q = 0; q < 4; ++q) n[q] = c[q];
      if (gl < GPB - 1) {
#pragma unroll
        for (int q = 0; q < 4; ++q)
          n[q] = *reinterpret_cast<const float4*>(zb + (size_t)(gl + 1) * KM + krow[q] * Mm + m4);
      }
      const int g = gblk * GPB + gl;
      const float4 hg = *reinterpret_cast<const float4*>(s_hsgrid + gl * Mm + m4);
      float num0 = 0, num1 = 0, num2 = 0, num3 = 0;
      float den0 = 0, den1 = 0, den2 = 0, den3 = 0;
#pragma unroll
      for (int q = 0; q < 4; ++q) {
        const float4 v = c[q];
        const float e0 = __expf(v.x), e1 = __expf(v.y), e2 = __expf(v.z), e3 = __expf(v.w);
        la_n[q][0] += e0 * hg.x; la_n[q][1] += e1 * hg.y;
        la_n[q][2] += e2 * hg.z; la_n[q][3] += e3 * hg.w;
        la_d[q][0] += e0; la_d[q][1] += e1; la_d[q][2] += e2; la_d[q][3] += e3;
        num0 += e0 * hk[q].x; num1 += e1 * hk[q].y;
        num2 += e2 * hk[q].z; num3 += e3 * hk[q].w;
        den0 += e0; den1 += e1; den2 += e2; den3 += e3;
        float ap = v.x * zw0 + v.y * zw1 + v.z * zw2 + v.w * zw3;
        ap += __shfl_xor(ap, 16); ap += __shfl_xor(ap, 8); ap += __shfl_xor(ap, 4);
        ap += __shfl_xor(ap, 2);  ap += __shfl_xor(ap, 1);
        if ((t & 31) == 0)
          a.att[((size_t)b * Gg + g) * Kk + krow[q]] = ap;
      }
      // combine the wave's two kgrps (lanes l, l+32 share m4)
      num0 += __shfl_xor(num0, 32); num1 += __shfl_xor(num1, 32);
      num2 += __shfl_xor(num2, 32); num3 += __shfl_xor(num3, 32);
      den0 += __shfl_xor(den0, 32); den1 += __shfl_xor(den1, 32);
      den2 += __shfl_xor(den2, 32); den3 += __shfl_xor(den3, 32);
      float* rnB = s_rn + (gl & 1) * 1024;
      float* rdB = s_rd + (gl & 1) * 1024;
      if ((t & 63) < 32) {
        *reinterpret_cast<float4*>(rnB + wv * Mm + m4) = make_float4(num0, num1, num2, num3);
        *reinterpret_cast<float4*>(rdB + wv * Mm + m4) = make_float4(den0, den1, den2, den3);
      }
      __syncthreads();
      if (t < Mm) {
        float nu = 0.f, de = 0.f;
#pragma unroll
        for (int ww = 0; ww < 8; ++ww) { nu += rnB[ww * Mm + t]; de += rdB[ww * Mm + t]; }
        const size_t go = ((size_t)b * Gg + g) * Mm + t;
        a.raNum[go] = nu; a.raDen[go] = de;    // raw sums; K2 divides
      }
#pragma unroll
      for (int q = 0; q < 4; ++q) c[q] = n[q];
    }

    const size_t base = ((size_t)(b * NCH + gblk)) * KM;
#pragma unroll
    for (int q = 0; q < 4; ++q) {
      *reinterpret_cast<float4*>(a.laNum + base + krow[q] * Mm + m4) =
          make_float4(la_n[q][0], la_n[q][1], la_n[q][2], la_n[q][3]);
      *reinterpret_cast<float4*>(a.laDen + base + krow[q] * Mm + m4) =
          make_float4(la_d[q][0], la_d[q][1], la_d[q][2], la_d[q][3]);
    }
  } else if (bid < 576) {
    // ---------------- Lk chain: lh = key@wcl.T + bl ; Lk = lh@wcR ----------
    float* s_w  = smem;          // 32 x 132 = 4224
    float* s_lh = smem + 4224;   // 8 x 132 = 1056
    const int blk = bid - 512;
    const int b = blk >> 3, k8 = blk & 7;
    const int m = t & 127, kq = t >> 7;    // 0..3; thread covers rows kq, kq+4
    const int k0 = k8 * 8 + kq, k1v = k0 + 4;
    float lh0 = 0.f, lh1 = 0.f;
    for (int hc = 0; hc < 4; ++hc) {
      for (int i = t; i < 4096; i += 512) {
        const int mm = i >> 5, hh = i & 31;
        s_w[hh * 132 + mm] = a.wcl_w[(size_t)mm * Mm + hc * 32 + hh];
      }
      __syncthreads();
      const float* kb0 = a.hs_key + ((size_t)b * Kk + k0) * Mm + hc * 32;   // wave-uniform
      const float* kb1 = a.hs_key + ((size_t)b * Kk + k1v) * Mm + hc * 32;
      for (int hh = 0; hh < 32; ++hh) {
        lh0 += kb0[hh] * s_w[hh * 132 + m];
        lh1 += kb1[hh] * s_w[hh * 132 + m];
      }
      __syncthreads();
    }
    s_lh[kq * 132 + m] = lh0 + a.wcl_b[m];
    s_lh[(kq + 4) * 132 + m] = lh1 + a.wcl_b[m];
    __syncthreads();
    float acc0 = 0.f, acc1 = 0.f;
    for (int mm = 0; mm < 128; ++mm) {
      const float wv_ = a.wcR_w[(size_t)mm * Mm + m];
      acc0 += s_lh[kq * 132 + mm] * wv_;
      acc1 += s_lh[(kq + 4) * 132 + mm] * wv_;
    }
    a.Lk[((size_t)b * Kk + k0) * Mm + m] = acc0;
    a.Lk[((size_t)b * Kk + k1v) * Mm + m] = acc1;
  } else {
    // ---------------- g-vector block ----------------
    float* s_fvec = smem;        // 260
    float* s_red  = smem + 260;  // 256
    if (t < 260) {
      float f = 0.f;
#pragma unroll
      for (int l = 0; l < 5; ++l) f += a.fin_w[l] * a.mapL_w[l * 260 + t];
      s_fvec[t] = f;
    }
    __syncthreads();
    const int h = t & 127, sel = t >> 7;   // 0..3
    for (int s = sel; s < 5; s += 4) {
      const float* W = (s == 0) ? a.wla_w : (s == 1) ? a.wlh_w :
                       (s == 2) ? a.kR_w : (s == 3) ? a.wra_w : a.wrh_w;
      const float* fv = (s < 3) ? s_fvec : (s_fvec + 132);
      float g = 0.f;
      for (int mm = 0; mm < 128; ++mm) g += fv[mm] * W[(size_t)mm * Mm + h];
      a.gbuf[s * 128 + h] = g;
    }
    if (t < 128) {
      s_red[t] = s_fvec[t] * (a.wla_b[t] + a.wlh_b[t] + a.kR_b[t]);
      s_red[128 + t] = s_fvec[132 + t] * (a.wra_b[t] + a.wrh_b[t]);
    }
    __syncthreads();
    if (t == 0) {
      float c1 = 0.f, c2 = 0.f;
      for (int i = 0; i < 128; ++i) { c1 += s_red[i]; c2 += s_red[128 + i]; }
      float C = a.fin_b[0];
#pragma unroll
      for (int l = 0; l < 5; ++l) C += a.fin_w[l] * a.mapL_b[l];
      // sum att_l = G = 512 exactly; sum att_r = K = 64 exactly
      a.gbuf[640] = C + 512.0f * c1 + 64.0f * c2;
#pragma unroll
      for (int e = 0; e < 4; ++e) a.gbuf[641 + e] = s_fvec[128 + e];
    }
  }
}

struct K2Args {
  const float *laNum, *laDen, *hs_key, *att, *raNum, *raDen, *hs_grid, *Lk, *hs_rec;
  const int *mask;
  const float *wRl, *gbuf;
  float *attlP, *attrPM, *attrPS, *attrPR, *pmT, *psT, *PSpT, *laDot, *keyDot;
};

// ===========================================================================
// K2: [0,64) laDot/keyDot | [64,128) att_l partials | [128,192) att_r with
//     inline rdot from raw ra sums | [192,704) scores tiles -> pm/ps/PSp
// ===========================================================================
__global__ __launch_bounds__(256) void K2(K2Args a) {
  __shared__ __align__(16) float smem[4944];
  const int bid = blockIdx.x;
  const int t = threadIdx.x;

  if (bid < 64) {
    // ---- laDot[b,k] = gv1 . (num/den), keyDot[b,k] = gv2 . key[b,k,:]
    const int b = bid >> 3, k8 = bid & 7;
    const int m = t & 127, kh = t >> 7;
    const float g1 = a.gbuf[m], g2 = a.gbuf[128 + m];
    float* sl = smem;            // 8*132
    float* sk = smem + 1056;     // 8*132
#pragma unroll
    for (int i = 0; i < 4; ++i) {
      const int k = k8 * 8 + kh * 4 + i;
      const float* np = a.laNum + (size_t)b * NCH * KM + (size_t)k * Mm + m;
      const float* dp = a.laDen + (size_t)b * NCH * KM + (size_t)k * Mm + m;
      float num = 0.f, den = 0.f;
#pragma unroll 8
      for (int p = 0; p < NCH; ++p) { num += np[(size_t)p * KM]; den += dp[(size_t)p * KM]; }
      sl[(kh * 4 + i) * 132 + m] = g1 * (num / den);
      sk[(kh * 4 + i) * 132 + m] = g2 * a.hs_key[((size_t)b * Kk + k) * Mm + m];
    }
    __syncthreads();
    const int rid = t >> 5, l32 = t & 31;
    float s1 = sl[rid * 132 + l32] + sl[rid * 132 + l32 + 32] +
               sl[rid * 132 + l32 + 64] + sl[rid * 132 + l32 + 96];
    float s2 = sk[rid * 132 + l32] + sk[rid * 132 + l32 + 32] +
               sk[rid * 132 + l32 + 64] + sk[rid * 132 + l32 + 96];
#pragma unroll
    for (int off = 16; off; off >>= 1) { s1 += __shfl_xor(s1, off); s2 += __shfl_xor(s2, off); }
    if (l32 == 0) {
      a.laDot[b * Kk + k8 * 8 + rid] = s1;
      a.keyDot[b * Kk + k8 * 8 + rid] = s2;
    }
  } else if (bid < 128) {
    // ---- att_l partials ----
    const int blk = bid - 64;
    const int b = blk >> 3, p = blk & 7;
    const int w = t >> 6, lane = t & 63;
    float acc = 0.f;
    for (int j = 0; j < 16; ++j) {
      const int g = p * 64 + w * 16 + j;
      const float av = a.att[((size_t)b * Gg + g) * Kk + lane];
      float mx = av;
      for (int off = 32; off; off >>= 1) mx = fmaxf(mx, __shfl_xor(mx, off));
      const float e = __expf(av - mx);
      float s = e;
      for (int off = 32; off; off >>= 1) s += __shfl_xor(s, off);
      acc += e / s;
    }
    float* sred = smem;
    sred[w * 64 + lane] = acc;
    __syncthreads();
    if (t < 64) a.attlP[(b * 8 + p) * 64 + t] = sred[t] + sred[64 + t] + sred[128 + t] + sred[192 + t];
  } else if (bid < 192) {
    // ---- att_r: inline rdot (from raw sums) + online partials per (b,gc) ----
    const int blk = bid - 128;
    const int b = blk >> 3, gc = blk & 7;
    float* s_gw   = smem;          // 256 (gw1, gw2)
    float* s_rdot = smem + 256;    // 64
    float* sm = smem + 320;        // 256
    float* ss = smem + 576;        // 256
    float* sr = smem + 832;        // 256
    s_gw[t] = a.gbuf[384 + t];
    __syncthreads();
    {
      const int gg = t >> 2, q = t & 3;
      const int g = gc * 64 + gg;
      const float* np = a.raNum + ((size_t)b * Gg + g) * Mm + q * 32;
      const float* dp = a.raDen + ((size_t)b * Gg + g) * Mm + q * 32;
      const float* hp = a.hs_grid + ((size_t)b * Gg + g) * Mm + q * 32;
      float acc = 0.f;
#pragma unroll
      for (int j4 = 0; j4 < 8; ++j4) {
        const float4 nv = *reinterpret_cast<const float4*>(np + j4 * 4);
        const float4 dv = *reinterpret_cast<const float4*>(dp + j4 * 4);
        const float4 hv = *reinterpret_cast<const float4*>(hp + j4 * 4);
        const int mb = q * 32 + j4 * 4;
        acc += s_gw[mb + 0] * (nv.x / dv.x) + s_gw[128 + mb + 0] * hv.x;
        acc += s_gw[mb + 1] * (nv.y / dv.y) + s_gw[128 + mb + 1] * hv.y;
        acc += s_gw[mb + 2] * (nv.z / dv.z) + s_gw[128 + mb + 2] * hv.z;
        acc += s_gw[mb + 3] * (nv.w / dv.w) + s_gw[128 + mb + 3] * hv.w;
      }
      acc += __shfl_xor(acc, 1);
      acc += __shfl_xor(acc, 2);
      if (q == 0) s_rdot[gg] = acc;
    }
    __syncthreads();
    const int k = t & 63, j4 = t >> 6;
    float m_ = -3.0e38f, s_ = 0.f, r_ = 0.f;
    for (int j = 0; j < 16; ++j) {
      const int gg = j4 * 16 + j;
      const float av = a.att[((size_t)b * Gg + gc * 64 + gg) * Kk + k];
      const float rv = s_rdot[gg];
      if (av > m_) {
        const float sc = __expf(m_ - av);
        s_ = s_ * sc + 1.0f; r_ = r_ * sc + rv; m_ = av;
      } else {
        const float e = __expf(av - m_);
        s_ += e; r_ += e * rv;
      }
    }
    sm[j4 * 64 + k] = m_; ss[j4 * 64 + k] = s_; sr[j4 * 64 + k] = r_;
    __syncthreads();
    if (t < 64) {
      float M = sm[t];
      for (int q = 1; q < 4; ++q) M = fmaxf(M, sm[q * 64 + t]);
      float S = 0.f, R = 0.f;
      for (int q = 0; q < 4; ++q) {
        const float e = __expf(sm[q * 64 + t] - M);
        S += ss[q * 64 + t] * e; R += sr[q * 64 + t] * e;
      }
      const int o = (b * 8 + gc) * 64 + t;
      a.attrPM[o] = M; a.attrPS[o] = S; a.attrPR[o] = R;
    }
  } else {
    // ---- scores tile: pm/ps/PSp partials (scores stay in registers) ----
    const int vb = bid - 192;
    const int b = vb >> 6, ntile = vb & 63;
    const int n0 = ntile * 16;
    const int k = t & 63;
    const int hq = __builtin_amdgcn_readfirstlane(t >> 6);
    float* s_acc = smem;          // 4096
    float* s_m   = smem + 4096;   // 256
    float* s_s   = smem + 4352;   // 256
    float* s_p   = smem + 4608;   // 256
    float* s_ru4 = smem + 4864;   // 64
    float* s_ru  = smem + 4928;   // 16
    float rLk[32];
    {
      const float* Lp = a.Lk + ((size_t)b * Kk + k) * Mm + hq * 32;
#pragma unroll
      for (int j = 0; j < 8; ++j) {
        const float4 v = *reinterpret_cast<const float4*>(Lp + j * 4);
        rLk[j * 4 + 0] = v.x; rLk[j * 4 + 1] = v.y;
        rLk[j * 4 + 2] = v.z; rLk[j * 4 + 3] = v.w;
      }
    }
    float acc[16];
    const float* rb = a.hs_rec + ((size_t)b * Nn + n0) * Mm + hq * 32;   // wave-uniform
#pragma unroll
    for (int r = 0; r < 16; ++r) {
      const float* rp = rb + r * Mm;
      float s = 0.f;
#pragma unroll
      for (int j4 = 0; j4 < 8; ++j4) {
        const float4 rv = *reinterpret_cast<const float4*>(rp + j4 * 4);
        s += rv.x * rLk[j4 * 4] + rv.y * rLk[j4 * 4 + 1] +
             rv.z * rLk[j4 * 4 + 2] + rv.w * rLk[j4 * 4 + 3];
      }
      acc[r] = s;
    }
#pragma unroll
    for (int r = 0; r < 16; ++r) s_acc[(hq * 16 + r) * 64 + k] = acc[r];
    if (t < 64) {   // ru[n] = gu . rec[n,:] partials
      const int rt = t >> 2, hc = t & 3;
      const float* rp = a.hs_rec + ((size_t)b * Nn + n0 + rt) * Mm + hc * 32;
      const float* gu = a.gbuf + 256 + hc * 32;
      float s = 0.f;
#pragma unroll
      for (int j = 0; j < 32; ++j) s += gu[j] * rp[j];
      s_ru4[rt * 4 + hc] = s;
    }
    __syncthreads();
    if (t < 16) s_ru[t] = s_ru4[t * 4] + s_ru4[t * 4 + 1] + s_ru4[t * 4 + 2] + s_ru4[t * 4 + 3];
    __syncthreads();
    const float wv = a.wRl[0];
    const bool msk = (a.mask[b * Kk + k] == 0);
    float m = -3.0e38f, ssum = 0.f, psum = 0.f;
    const int hq4 = (t >> 6) * 4;
#pragma unroll
    for (int q = 0; q < 4; ++q) {
      const int r = hq4 + q;
      float v = s_acc[r * 64 + k] + s_acc[(16 + r) * 64 + k] +
                s_acc[(32 + r) * 64 + k] + s_acc[(48 + r) * 64 + k];
      v = msk ? -1e10f : wv * v;
      const float runow = s_ru[r];
      if (v > m) {
        const float sc = __expf(m - v);
        ssum = ssum * sc + 1.0f; psum = psum * sc + runow; m = v;
      } else {
        const float e = __expf(v - m);
        ssum += e; psum += e * runow;
      }
    }
    s_m[(t >> 6) * 64 + k] = m; s_s[(t >> 6) * 64 + k] = ssum; s_p[(t >> 6) * 64 + k] = psum;
    __syncthreads();
    if (t < 64) {
      float M = fmaxf(fmaxf(s_m[t], s_m[64 + t]), fmaxf(s_m[128 + t], s_m[192 + t]));
      float S = 0.f, P = 0.f;
#pragma unroll
      for (int q = 0; q < 4; ++q) {
        const float e = __expf(s_m[q * 64 + t] - M);
        S += s_s[q * 64 + t] * e; P += s_p[q * 64 + t] * e;
      }
      const size_t o = ((size_t)b * 64 + ntile) * 64 + t;
      a.pmT[o] = M; a.psT[o] = S; a.PSpT[o] = P;
    }
  }
}

// ===========================================================================
// K3: per-b finale (8 blocks x 64 threads): scalar assembly
// ===========================================================================
__global__ __launch_bounds__(64) void K3(
    const float* __restrict__ attlP, const float* __restrict__ pmT,
    const float* __restrict__ psT, const float* __restrict__ PSpT,
    const float* __restrict__ attrPM, const float* __restrict__ attrPS,
    const float* __restrict__ attrPR,
    const float* __restrict__ laDot, const float* __restrict__ keyDot,
    const float* __restrict__ gbuf, const float* __restrict__ lig_rep,
    float* __restrict__ out)
{
  const int b = blockIdx.x, t = threadIdx.x;   // t = k
  float attl = 0.f;
#pragma unroll
  for (int p = 0; p < 8; ++p) attl += attlP[(b * 8 + p) * 64 + t];
  float M = -3.0e38f, S = 0.f, P = 0.f;
  for (int nt = 0; nt < 64; ++nt) {
    const size_t o = ((size_t)b * 64 + nt) * 64 + t;
    const float pm_ = pmT[o], ps_ = psT[o], pp = PSpT[o];
    if (pm_ > M) {
      const float sc = __expf(M - pm_);
      S = S * sc + ps_; P = P * sc + pp; M = pm_;
    } else {
      const float e = __expf(pm_ - M);
      S += ps_ * e; P += pp * e;
    }
  }
  float Mr = -3.0e38f, Sr = 0.f, Rr = 0.f;
  for (int p = 0; p < 8; ++p) {
    const int o = (b * 8 + p) * 64 + t;
    const float pm_ = attrPM[o], ps_ = attrPS[o], pr_ = attrPR[o];
    if (pm_ > Mr) {
      const float sc = __expf(Mr - pm_);
      Sr = Sr * sc + ps_; Rr = Rr * sc + pr_; Mr = pm_;
    } else {
      const float e = __expf(pm_ - Mr);
      Sr += ps_ * e; Rr += pr_ * e;
    }
  }
  float val = attl * (laDot[b * 64 + t] + keyDot[b * 64 + t] + P / S) + Rr / Sr;
#pragma unroll
  for (int off = 32; off; off >>= 1) val += __shfl_xor(val, off);
  if (t == 0) {
    float o = val + gbuf[640];
#pragma unroll
    for (int e = 0; e < 4; ++e) o += gbuf[641 + e] * lig_rep[b * 4 + e];
    out[b] = o;
  }
}

// ---------------------------------------------------------------------------
extern "C" void kernel_launch(void* const* d_in, const int* in_sizes, int n_in,
                              void* d_out, int out_size, void* d_ws, size_t ws_size,
                              hipStream_t stream) {
  float* w = (float*)d_ws;
  float* gbuf  = w;                       // 1024
  float* att   = gbuf + 1024;             // 262144
  float* laNum = att + Bb * Gg * Kk;      // 4194304
  float* laDen = laNum + Bb * NCH * KM;   // 4194304
  float* raNum = laDen + Bb * NCH * KM;   // 524288
  float* raDen = raNum + Bb * Gg * Mm;    // 524288
  float* Lk    = raDen + Bb * Gg * Mm;    // 65536
  float* attlP = Lk + Bb * Kk * Mm;       // 4096
  float* pmT   = attlP + Bb * 8 * 64;     // 32768
  float* psT   = pmT + Bb * 64 * 64;      // 32768
  float* PSpT  = psT + Bb * 64 * 64;      // 32768
  float* laDot = PSpT + Bb * 64 * 64;     // 512
  float* keyDot = laDot + Bb * Kk;        // 512
  float* attrPM = keyDot + Bb * Kk;       // 4096
  float* attrPS = attrPM + Bb * 8 * 64;   // 4096
  float* attrPR = attrPS + Bb * 8 * 64;   // 4096

  K1Args a1;
  a1.z = (const float*)d_in[0];
  a1.hs_grid = (const float*)d_in[1];
  a1.hs_key = (const float*)d_in[2];
  a1.z1w = (const float*)d_in[15];
  a1.wra_w = (const float*)d_in[7];  a1.wra_b = (const float*)d_in[8];
  a1.wrh_w = (const float*)d_in[9];  a1.wrh_b = (const float*)d_in[10];
  a1.wla_w = (const float*)d_in[11]; a1.wla_b = (const float*)d_in[12];
  a1.wlh_w = (const float*)d_in[13]; a1.wlh_b = (const float*)d_in[14];
  a1.wcl_w = (const float*)d_in[19]; a1.wcl_b = (const float*)d_in[20];
  a1.wcR_w = (const float*)d_in[17];
  a1.kR_w  = (const float*)d_in[21]; a1.kR_b = (const float*)d_in[22];
  a1.mapL_w = (const float*)d_in[23]; a1.mapL_b = (const float*)d_in[24];
  a1.fin_w = (const float*)d_in[25]; a1.fin_b = (const float*)d_in[26];
  a1.att = att; a1.laNum = laNum; a1.laDen = laDen;
  a1.raNum = raNum; a1.raDen = raDen; a1.Lk = Lk; a1.gbuf = gbuf;

  K2Args a2;
  a2.laNum = laNum; a2.laDen = laDen;
  a2.hs_key = (const float*)d_in[2];
  a2.att = att; a2.raNum = raNum; a2.raDen = raDen;
  a2.hs_grid = (const float*)d_in[1];
  a2.Lk = Lk;
  a2.hs_rec = (const float*)d_in[4];
  a2.mask = (const int*)d_in[6];
  a2.wRl = (const float*)d_in[5];
  a2.gbuf = gbuf;
  a2.attlP = attlP;
  a2.attrPM = attrPM; a2.attrPS = attrPS; a2.attrPR = attrPR;
  a2.pmT = pmT; a2.psT = psT; a2.PSpT = PSpT;
  a2.laDot = laDot; a2.keyDot = keyDot;

  K1<<<577, 512, 0, stream>>>(a1);
  K2<<<704, 256, 0, stream>>>(a2);
  K3<<<Bb, 64, 0, stream>>>(attlP, pmT, psT, PSpT, attrPM, attrPS, attrPR,
                            laDot, keyDot, gbuf, (const float*)d_in[3],
                            (float*)d_out);
}

// Round 11
// 109.200 us; speedup vs baseline: 1.7150x; 1.1010x over previous
//
#include <hip/hip_runtime.h>

// Problem dims
#define Bb 8
#define Gg 512
#define Kk 64
#define Nn 1024
#define Mm 128
#define KM 8192           // Kk*Mm
#define GPB 8             // g per z-block
#define NCH 64            // Gg/GPB partial chunks

struct K1Args {
  const float *z, *hs_grid, *hs_key, *z1w;
  const float *wra_w, *wrh_w, *wla_w, *wlh_w, *kR_w;
  const float *wla_b, *wlh_b, *kR_b, *wra_b, *wrh_b;
  const float *wcl_w, *wcl_b, *wcR_w;
  const float *mapL_w, *mapL_b, *fin_w, *fin_b;
  float *att, *laNum, *laDen, *raNum, *raDen, *Lk, *gbuf;
};

// ===========================================================================
// K1 (512 threads; launch_bounds(512,2) -> VGPR cap 128, no spills):
//  [0,512)   z-pass: att, la partials, raw ra num/den sums  (pure streaming)
//  [512,576) Lk chain
//  [576]     g-vector block
// gbuf: gv1[0:128] gv2[128:256] gu[256:384] gw1[384:512] gw2[512:640]
//       Cfull[640] fvecL[641:645]
// ===========================================================================
__global__ __launch_bounds__(512, 2) void K1(K1Args a) {
  __shared__ __align__(16) float smem[5376];   // 21.5 KB
  const int bid = blockIdx.x;
  const int t = threadIdx.x;

  if (bid < 512) {
    // ---------------- z-pass ----------------
    float* s_hsgrid = smem;          // 1024
    float* s_rn     = smem + 1024;   // 2 x 1024 (double buffered)
    float* s_rd     = smem + 3072;   // 2 x 1024

    const int b = bid >> 6;
    const int gblk = bid & 63;
    const int m4 = (t & 31) << 2;
    const int kgrp = (t >> 5) & 15;  // 0..15
    const int wv = t >> 6;           // 0..7

    const float* hgb = a.hs_grid + ((size_t)b * Gg + gblk * GPB) * Mm;
    for (int idx = t; idx < GPB * Mm; idx += 512) s_hsgrid[idx] = hgb[idx];

    int krow[4];
    krow[0] = 2 * kgrp;      krow[1] = 2 * kgrp + 1;
    krow[2] = 2 * kgrp + 32; krow[3] = 2 * kgrp + 33;
    float4 hk[4];
#pragma unroll
    for (int q = 0; q < 4; ++q)
      hk[q] = *reinterpret_cast<const float4*>(a.hs_key + (size_t)b * KM + krow[q] * Mm + m4);
    const float zw0 = a.z1w[m4], zw1 = a.z1w[m4 + 1], zw2 = a.z1w[m4 + 2], zw3 = a.z1w[m4 + 3];

    float la_n[4][4], la_d[4][4];
#pragma unroll
    for (int q = 0; q < 4; ++q)
#pragma unroll
      for (int j = 0; j < 4; ++j) { la_n[q][j] = 0.f; la_d[q][j] = 0.f; }

    const float* zb = a.z + ((size_t)b * Gg + gblk * GPB) * (size_t)KM;
    float4 c[4];
#pragma unroll
    for (int q = 0; q < 4; ++q)
      c[q] = *reinterpret_cast<const float4*>(zb + krow[q] * Mm + m4);

    __syncthreads();

    for (int gl = 0; gl < GPB; ++gl) {
      float4 n[4];
#pragma unroll
      for (int q = 0; q < 4; ++q) n[q] = c[q];
      if (gl < GPB - 1) {
#pragma unroll
        for (int q = 0; q < 4; ++q)
          n[q] = *reinterpret_cast<const float4*>(zb + (size_t)(gl + 1) * KM + krow[q] * Mm + m4);
      }
      const int g = gblk * GPB + gl;
      const float4 hg = *reinterpret_cast<const float4*>(s_hsgrid + gl * Mm + m4);
      float num0 = 0, num1 = 0, num2 = 0, num3 = 0;
      float den0 = 0, den1 = 0, den2 = 0, den3 = 0;
#pragma unroll
      for (int q = 0; q < 4; ++q) {
        const float4 v = c[q];
        const float e0 = __expf(v.x), e1 = __expf(v.y), e2 = __expf(v.z), e3 = __expf(v.w);
        la_n[q][0] += e0 * hg.x; la_n[q][1] += e1 * hg.y;
        la_n[q][2] += e2 * hg.z; la_n[q][3] += e3 * hg.w;
        la_d[q][0] += e0; la_d[q][1] += e1; la_d[q][2] += e2; la_d[q][3] += e3;
        num0 += e0 * hk[q].x; num1 += e1 * hk[q].y;
        num2 += e2 * hk[q].z; num3 += e3 * hk[q].w;
        den0 += e0; den1 += e1; den2 += e2; den3 += e3;
        float ap = v.x * zw0 + v.y * zw1 + v.z * zw2 + v.w * zw3;
        ap += __shfl_xor(ap, 16); ap += __shfl_xor(ap, 8); ap += __shfl_xor(ap, 4);
        ap += __shfl_xor(ap, 2);  ap += __shfl_xor(ap, 1);
        if ((t & 31) == 0)
          a.att[((size_t)b * Gg + g) * Kk + krow[q]] = ap;
      }
      // combine the wave's two kgrps (lanes l, l+32 share m4)
      num0 += __shfl_xor(num0, 32); num1 += __shfl_xor(num1, 32);
      num2 += __shfl_xor(num2, 32); num3 += __shfl_xor(num3, 32);
      den0 += __shfl_xor(den0, 32); den1 += __shfl_xor(den1, 32);
      den2 += __shfl_xor(den2, 32); den3 += __shfl_xor(den3, 32);
      float* rnB = s_rn + (gl & 1) * 1024;
      float* rdB = s_rd + (gl & 1) * 1024;
      if ((t & 63) < 32) {
        *reinterpret_cast<float4*>(rnB + wv * Mm + m4) = make_float4(num0, num1, num2, num3);
        *reinterpret_cast<float4*>(rdB + wv * Mm + m4) = make_float4(den0, den1, den2, den3);
      }
      __syncthreads();
      if (t < Mm) {
        float nu = 0.f, de = 0.f;
#pragma unroll
        for (int ww = 0; ww < 8; ++ww) { nu += rnB[ww * Mm + t]; de += rdB[ww * Mm + t]; }
        const size_t go = ((size_t)b * Gg + g) * Mm + t;
        a.raNum[go] = nu; a.raDen[go] = de;    // raw sums; K2 divides
      }
#pragma unroll
      for (int q = 0; q < 4; ++q) c[q] = n[q];
    }

    const size_t base = ((size_t)(b * NCH + gblk)) * KM;
#pragma unroll
    for (int q = 0; q < 4; ++q) {
      *reinterpret_cast<float4*>(a.laNum + base + krow[q] * Mm + m4) =
          make_float4(la_n[q][0], la_n[q][1], la_n[q][2], la_n[q][3]);
      *reinterpret_cast<float4*>(a.laDen + base + krow[q] * Mm + m4) =
          make_float4(la_d[q][0], la_d[q][1], la_d[q][2], la_d[q][3]);
    }
  } else if (bid < 576) {
    // ---------------- Lk chain: lh = key@wcl.T + bl ; Lk = lh@wcR ----------
    float* s_w  = smem;          // 32 x 132 = 4224
    float* s_lh = smem + 4224;   // 8 x 132 = 1056
    const int blk = bid - 512;
    const int b = blk >> 3, k8 = blk & 7;
    const int m = t & 127, kq = t >> 7;    // 0..3; thread covers rows kq, kq+4
    const int k0 = k8 * 8 + kq, k1v = k0 + 4;
    float lh0 = 0.f, lh1 = 0.f;
    for (int hc = 0; hc < 4; ++hc) {
      for (int i = t; i < 4096; i += 512) {
        const int mm = i >> 5, hh = i & 31;
        s_w[hh * 132 + mm] = a.wcl_w[(size_t)mm * Mm + hc * 32 + hh];
      }
      __syncthreads();
      const float* kb0 = a.hs_key + ((size_t)b * Kk + k0) * Mm + hc * 32;   // wave-uniform
      const float* kb1 = a.hs_key + ((size_t)b * Kk + k1v) * Mm + hc * 32;
      for (int hh = 0; hh < 32; ++hh) {
        lh0 += kb0[hh] * s_w[hh * 132 + m];
        lh1 += kb1[hh] * s_w[hh * 132 + m];
      }
      __syncthreads();
    }
    s_lh[kq * 132 + m] = lh0 + a.wcl_b[m];
    s_lh[(kq + 4) * 132 + m] = lh1 + a.wcl_b[m];
    __syncthreads();
    float acc0 = 0.f, acc1 = 0.f;
    for (int mm = 0; mm < 128; ++mm) {
      const float wv_ = a.wcR_w[(size_t)mm * Mm + m];
      acc0 += s_lh[kq * 132 + mm] * wv_;
      acc1 += s_lh[(kq + 4) * 132 + mm] * wv_;
    }
    a.Lk[((size_t)b * Kk + k0) * Mm + m] = acc0;
    a.Lk[((size_t)b * Kk + k1v) * Mm + m] = acc1;
  } else {
    // ---------------- g-vector block ----------------
    float* s_fvec = smem;        // 260
    float* s_red  = smem + 260;  // 256
    if (t < 260) {
      float f = 0.f;
#pragma unroll
      for (int l = 0; l < 5; ++l) f += a.fin_w[l] * a.mapL_w[l * 260 + t];
      s_fvec[t] = f;
    }
    __syncthreads();
    const int h = t & 127, sel = t >> 7;   // 0..3
    for (int s = sel; s < 5; s += 4) {
      const float* W = (s == 0) ? a.wla_w : (s == 1) ? a.wlh_w :
                       (s == 2) ? a.kR_w : (s == 3) ? a.wra_w : a.wrh_w;
      const float* fv = (s < 3) ? s_fvec : (s_fvec + 132);
      float g = 0.f;
      for (int mm = 0; mm < 128; ++mm) g += fv[mm] * W[(size_t)mm * Mm + h];
      a.gbuf[s * 128 + h] = g;
    }
    if (t < 128) {
      s_red[t] = s_fvec[t] * (a.wla_b[t] + a.wlh_b[t] + a.kR_b[t]);
      s_red[128 + t] = s_fvec[132 + t] * (a.wra_b[t] + a.wrh_b[t]);
    }
    __syncthreads();
    if (t == 0) {
      float c1 = 0.f, c2 = 0.f;
      for (int i = 0; i < 128; ++i) { c1 += s_red[i]; c2 += s_red[128 + i]; }
      float C = a.fin_b[0];
#pragma unroll
      for (int l = 0; l < 5; ++l) C += a.fin_w[l] * a.mapL_b[l];
      // sum att_l = G = 512 exactly; sum att_r = K = 64 exactly
      a.gbuf[640] = C + 512.0f * c1 + 64.0f * c2;
#pragma unroll
      for (int e = 0; e < 4; ++e) a.gbuf[641 + e] = s_fvec[128 + e];
    }
  }
}

struct K2Args {
  const float *laNum, *laDen, *hs_key, *att, *raNum, *raDen, *hs_grid, *Lk, *hs_rec;
  const int *mask;
  const float *wRl, *gbuf;
  float *attlP, *attrPM, *attrPS, *attrPR, *pmT, *psT, *PSpT, *laDot, *keyDot;
};

// ===========================================================================
// K2: [0,64) laDot/keyDot | [64,128) att_l partials | [128,192) att_r with
//     inline rdot from raw ra sums | [192,704) scores tiles -> pm/ps/PSp
// ===========================================================================
__global__ __launch_bounds__(256) void K2(K2Args a) {
  __shared__ __align__(16) float smem[4944];
  const int bid = blockIdx.x;
  const int t = threadIdx.x;

  if (bid < 64) {
    // ---- laDot[b,k] = gv1 . (num/den), keyDot[b,k] = gv2 . key[b,k,:]
    const int b = bid >> 3, k8 = bid & 7;
    const int m = t & 127, kh = t >> 7;
    const float g1 = a.gbuf[m], g2 = a.gbuf[128 + m];
    float* sl = smem;            // 8*132
    float* sk = smem + 1056;     // 8*132
#pragma unroll
    for (int i = 0; i < 4; ++i) {
      const int k = k8 * 8 + kh * 4 + i;
      const float* np = a.laNum + (size_t)b * NCH * KM + (size_t)k * Mm + m;
      const float* dp = a.laDen + (size_t)b * NCH * KM + (size_t)k * Mm + m;
      float num = 0.f, den = 0.f;
#pragma unroll 8
      for (int p = 0; p < NCH; ++p) { num += np[(size_t)p * KM]; den += dp[(size_t)p * KM]; }
      sl[(kh * 4 + i) * 132 + m] = g1 * (num / den);
      sk[(kh * 4 + i) * 132 + m] = g2 * a.hs_key[((size_t)b * Kk + k) * Mm + m];
    }
    __syncthreads();
    const int rid = t >> 5, l32 = t & 31;
    float s1 = sl[rid * 132 + l32] + sl[rid * 132 + l32 + 32] +
               sl[rid * 132 + l32 + 64] + sl[rid * 132 + l32 + 96];
    float s2 = sk[rid * 132 + l32] + sk[rid * 132 + l32 + 32] +
               sk[rid * 132 + l32 + 64] + sk[rid * 132 + l32 + 96];
#pragma unroll
    for (int off = 16; off; off >>= 1) { s1 += __shfl_xor(s1, off); s2 += __shfl_xor(s2, off); }
    if (l32 == 0) {
      a.laDot[b * Kk + k8 * 8 + rid] = s1;
      a.keyDot[b * Kk + k8 * 8 + rid] = s2;
    }
  } else if (bid < 128) {
    // ---- att_l partials ----
    const int blk = bid - 64;
    const int b = blk >> 3, p = blk & 7;
    const int w = t >> 6, lane = t & 63;
    float acc = 0.f;
    for (int j = 0; j < 16; ++j) {
      const int g = p * 64 + w * 16 + j;
      const float av = a.att[((size_t)b * Gg + g) * Kk + lane];
      float mx = av;
      for (int off = 32; off; off >>= 1) mx = fmaxf(mx, __shfl_xor(mx, off));
      const float e = __expf(av - mx);
      float s = e;
      for (int off = 32; off; off >>= 1) s += __shfl_xor(s, off);
      acc += e / s;
    }
    float* sred = smem;
    sred[w * 64 + lane] = acc;
    __syncthreads();
    if (t < 64) a.attlP[(b * 8 + p) * 64 + t] = sred[t] + sred[64 + t] + sred[128 + t] + sred[192 + t];
  } else if (bid < 192) {
    // ---- att_r: inline rdot (from raw sums) + online partials per (b,gc) ----
    const int blk = bid - 128;
    const int b = blk >> 3, gc = blk & 7;
    float* s_gw   = smem;          // 256 (gw1, gw2)
    float* s_rdot = smem + 256;    // 64
    float* sm = smem + 320;        // 256
    float* ss = smem + 576;        // 256
    float* sr = smem + 832;        // 256
    s_gw[t] = a.gbuf[384 + t];
    __syncthreads();
    {
      const int gg = t >> 2, q = t & 3;
      const int g = gc * 64 + gg;
      const float* np = a.raNum + ((size_t)b * Gg + g) * Mm + q * 32;
      const float* dp = a.raDen + ((size_t)b * Gg + g) * Mm + q * 32;
      const float* hp = a.hs_grid + ((size_t)b * Gg + g) * Mm + q * 32;
      float acc = 0.f;
#pragma unroll
      for (int j4 = 0; j4 < 8; ++j4) {
        const float4 nv = *reinterpret_cast<const float4*>(np + j4 * 4);
        const float4 dv = *reinterpret_cast<const float4*>(dp + j4 * 4);
        const float4 hv = *reinterpret_cast<const float4*>(hp + j4 * 4);
        const int mb = q * 32 + j4 * 4;
        acc += s_gw[mb + 0] * (nv.x / dv.x) + s_gw[128 + mb + 0] * hv.x;
        acc += s_gw[mb + 1] * (nv.y / dv.y) + s_gw[128 + mb + 1] * hv.y;
        acc += s_gw[mb + 2] * (nv.z / dv.z) + s_gw[128 + mb + 2] * hv.z;
        acc += s_gw[mb + 3] * (nv.w / dv.w) + s_gw[128 + mb + 3] * hv.w;
      }
      acc += __shfl_xor(acc, 1);
      acc += __shfl_xor(acc, 2);
      if (q == 0) s_rdot[gg] = acc;
    }
    __syncthreads();
    const int k = t & 63, j4 = t >> 6;
    float m_ = -3.0e38f, s_ = 0.f, r_ = 0.f;
    for (int j = 0; j < 16; ++j) {
      const int gg = j4 * 16 + j;
      const float av = a.att[((size_t)b * Gg + gc * 64 + gg) * Kk + k];
      const float rv = s_rdot[gg];
      if (av > m_) {
        const float sc = __expf(m_ - av);
        s_ = s_ * sc + 1.0f; r_ = r_ * sc + rv; m_ = av;
      } else {
        const float e = __expf(av - m_);
        s_ += e; r_ += e * rv;
      }
    }
    sm[j4 * 64 + k] = m_; ss[j4 * 64 + k] = s_; sr[j4 * 64 + k] = r_;
    __syncthreads();
    if (t < 64) {
      float M = sm[t];
      for (int q = 1; q < 4; ++q) M = fmaxf(M, sm[q * 64 + t]);
      float S = 0.f, R = 0.f;
      for (int q = 0; q < 4; ++q) {
        const float e = __expf(sm[q * 64 + t] - M);
        S += ss[q * 64 + t] * e; R += sr[q * 64 + t] * e;
      }
      const int o = (b * 8 + gc) * 64 + t;
      a.attrPM[o] = M; a.attrPS[o] = S; a.attrPR[o] = R;
    }
  } else {
    // ---- scores tile: pm/ps/PSp partials (scores stay in registers) ----
    const int vb = bid - 192;
    const int b = vb >> 6, ntile = vb & 63;
    const int n0 = ntile * 16;
    const int k = t & 63;
    const int hq = __builtin_amdgcn_readfirstlane(t >> 6);
    float* s_acc = smem;          // 4096
    float* s_m   = smem + 4096;   // 256
    float* s_s   = smem + 4352;   // 256
    float* s_p   = smem + 4608;   // 256
    float* s_ru4 = smem + 4864;   // 64
    float* s_ru  = smem + 4928;   // 16
    float rLk[32];
    {
      const float* Lp = a.Lk + ((size_t)b * Kk + k) * Mm + hq * 32;
#pragma unroll
      for (int j = 0; j < 8; ++j) {
        const float4 v = *reinterpret_cast<const float4*>(Lp + j * 4);
        rLk[j * 4 + 0] = v.x; rLk[j * 4 + 1] = v.y;
        rLk[j * 4 + 2] = v.z; rLk[j * 4 + 3] = v.w;
      }
    }
    float acc[16];
    const float* rb = a.hs_rec + ((size_t)b * Nn + n0) * Mm + hq * 32;   // wave-uniform
#pragma unroll
    for (int r = 0; r < 16; ++r) {
      const float* rp = rb + r * Mm;
      float s = 0.f;
#pragma unroll
      for (int j4 = 0; j4 < 8; ++j4) {
        const float4 rv = *reinterpret_cast<const float4*>(rp + j4 * 4);
        s += rv.x * rLk[j4 * 4] + rv.y * rLk[j4 * 4 + 1] +
             rv.z * rLk[j4 * 4 + 2] + rv.w * rLk[j4 * 4 + 3];
      }
      acc[r] = s;
    }
#pragma unroll
    for (int r = 0; r < 16; ++r) s_acc[(hq * 16 + r) * 64 + k] = acc[r];
    if (t < 64) {   // ru[n] = gu . rec[n,:] partials
      const int rt = t >> 2, hc = t & 3;
      const float* rp = a.hs_rec + ((size_t)b * Nn + n0 + rt) * Mm + hc * 32;
      const float* gu = a.gbuf + 256 + hc * 32;
      float s = 0.f;
#pragma unroll
      for (int j = 0; j < 32; ++j) s += gu[j] * rp[j];
      s_ru4[rt * 4 + hc] = s;
    }
    __syncthreads();
    if (t < 16) s_ru[t] = s_ru4[t * 4] + s_ru4[t * 4 + 1] + s_ru4[t * 4 + 2] + s_ru4[t * 4 + 3];
    __syncthreads();
    const float wv = a.wRl[0];
    const bool msk = (a.mask[b * Kk + k] == 0);
    float m = -3.0e38f, ssum = 0.f, psum = 0.f;
    const int hq4 = (t >> 6) * 4;
#pragma unroll
    for (int q = 0; q < 4; ++q) {
      const int r = hq4 + q;
      float v = s_acc[r * 64 + k] + s_acc[(16 + r) * 64 + k] +
                s_acc[(32 + r) * 64 + k] + s_acc[(48 + r) * 64 + k];
      v = msk ? -1e10f : wv * v;
      const float runow = s_ru[r];
      if (v > m) {
        const float sc = __expf(m - v);
        ssum = ssum * sc + 1.0f; psum = psum * sc + runow; m = v;
      } else {
        const float e = __expf(v - m);
        ssum += e; psum += e * runow;
      }
    }
    s_m[(t >> 6) * 64 + k] = m; s_s[(t >> 6) * 64 + k] = ssum; s_p[(t >> 6) * 64 + k] = psum;
    __syncthreads();
    if (t < 64) {
      float M = fmaxf(fmaxf(s_m[t], s_m[64 + t]), fmaxf(s_m[128 + t], s_m[192 + t]));
      float S = 0.f, P = 0.f;
#pragma unroll
      for (int q = 0; q < 4; ++q) {
        const float e = __expf(s_m[q * 64 + t] - M);
        S += s_s[q * 64 + t] * e; P += s_p[q * 64 + t] * e;
      }
      const size_t o = ((size_t)b * 64 + ntile) * 64 + t;
      a.pmT[o] = M; a.psT[o] = S; a.PSpT[o] = P;
    }
  }
}

// ===========================================================================
// K3: per-b finale (8 blocks x 64 threads): scalar assembly
// ===========================================================================
__global__ __launch_bounds__(64) void K3(
    const float* __restrict__ attlP, const float* __restrict__ pmT,
    const float* __restrict__ psT, const float* __restrict__ PSpT,
    const float* __restrict__ attrPM, const float* __restrict__ attrPS,
    const float* __restrict__ attrPR,
    const float* __restrict__ laDot, const float* __restrict__ keyDot,
    const float* __restrict__ gbuf, const float* __restrict__ lig_rep,
    float* __restrict__ out)
{
  const int b = blockIdx.x, t = threadIdx.x;   // t = k
  float attl = 0.f;
#pragma unroll
  for (int p = 0; p < 8; ++p) attl += attlP[(b * 8 + p) * 64 + t];
  float M = -3.0e38f, S = 0.f, P = 0.f;
  for (int nt = 0; nt < 64; ++nt) {
    const size_t o = ((size_t)b * 64 + nt) * 64 + t;
    const float pm_ = pmT[o], ps_ = psT[o], pp = PSpT[o];
    if (pm_ > M) {
      const float sc = __expf(M - pm_);
      S = S * sc + ps_; P = P * sc + pp; M = pm_;
    } else {
      const float e = __expf(pm_ - M);
      S += ps_ * e; P += pp * e;
    }
  }
  float Mr = -3.0e38f, Sr = 0.f, Rr = 0.f;
  for (int p = 0; p < 8; ++p) {
    const int o = (b * 8 + p) * 64 + t;
    const float pm_ = attrPM[o], ps_ = attrPS[o], pr_ = attrPR[o];
    if (pm_ > Mr) {
      const float sc = __expf(Mr - pm_);
      Sr = Sr * sc + ps_; Rr = Rr * sc + pr_; Mr = pm_;
    } else {
      const float e = __expf(pm_ - Mr);
      Sr += ps_ * e; Rr += pr_ * e;
    }
  }
  float val = attl * (laDot[b * 64 + t] + keyDot[b * 64 + t] + P / S) + Rr / Sr;
#pragma unroll
  for (int off = 32; off; off >>= 1) val += __shfl_xor(val, off);
  if (t == 0) {
    float o = val + gbuf[640];
#pragma unroll
    for (int e = 0; e < 4; ++e) o += gbuf[641 + e] * lig_rep[b * 4 + e];
    out[b] = o;
  }
}

// ---------------------------------------------------------------------------
extern "C" void kernel_launch(void* const* d_in, const int* in_sizes, int n_in,
                              void* d_out, int out_size, void* d_ws, size_t ws_size,
                              hipStream_t stream) {
  float* w = (float*)d_ws;
  float* gbuf  = w;                       // 1024
  float* att   = gbuf + 1024;             // 262144
  float* laNum = att + Bb * Gg * Kk;      // 4194304
  float* laDen = laNum + Bb * NCH * KM;   // 4194304
  float* raNum = laDen + Bb * NCH * KM;   // 524288
  float* raDen = raNum + Bb * Gg * Mm;    // 524288
  float* Lk    = raDen + Bb * Gg * Mm;    // 65536
  float* attlP = Lk + Bb * Kk * Mm;       // 4096
  float* pmT   = attlP + Bb * 8 * 64;     // 32768
  float* psT   = pmT + Bb * 64 * 64;      // 32768
  float* PSpT  = psT + Bb * 64 * 64;      // 32768
  float* laDot = PSpT + Bb * 64 * 64;     // 512
  float* keyDot = laDot + Bb * Kk;        // 512
  float* attrPM = keyDot + Bb * Kk;       // 4096
  float* attrPS = attrPM + Bb * 8 * 64;   // 4096
  float* attrPR = attrPS + Bb * 8 * 64;   // 4096

  K1Args a1;
  a1.z = (const float*)d_in[0];
  a1.hs_grid = (const float*)d_in[1];
  a1.hs_key = (const float*)d_in[2];
  a1.z1w = (const float*)d_in[15];
  a1.wra_w = (const float*)d_in[7];  a1.wra_b = (const float*)d_in[8];
  a1.wrh_w = (const float*)d_in[9];  a1.wrh_b = (const float*)d_in[10];
  a1.wla_w = (const float*)d_in[11]; a1.wla_b = (const float*)d_in[12];
  a1.wlh_w = (const float*)d_in[13]; a1.wlh_b = (const float*)d_in[14];
  a1.wcl_w = (const float*)d_in[19]; a1.wcl_b = (const float*)d_in[20];
  a1.wcR_w = (const float*)d_in[17];
  a1.kR_w  = (const float*)d_in[21]; a1.kR_b = (const float*)d_in[22];
  a1.mapL_w = (const float*)d_in[23]; a1.mapL_b = (const float*)d_in[24];
  a1.fin_w = (const float*)d_in[25]; a1.fin_b = (const float*)d_in[26];
  a1.att = att; a1.laNum = laNum; a1.laDen = laDen;
  a1.raNum = raNum; a1.raDen = raDen; a1.Lk = Lk; a1.gbuf = gbuf;

  K2Args a2;
  a2.laNum = laNum; a2.laDen = laDen;
  a2.hs_key = (const float*)d_in[2];
  a2.att = att; a2.raNum = raNum; a2.raDen = raDen;
  a2.hs_grid = (const float*)d_in[1];
  a2.Lk = Lk;
  a2.hs_rec = (const float*)d_in[4];
  a2.mask = (const int*)d_in[6];
  a2.wRl = (const float*)d_in[5];
  a2.gbuf = gbuf;
  a2.attlP = attlP;
  a2.attrPM = attrPM; a2.attrPS = attrPS; a2.attrPR = attrPR;
  a2.pmT = pmT; a2.psT = psT; a2.PSpT = PSpT;
  a2.laDot = laDot; a2.keyDot = keyDot;

  K1<<<577, 512, 0, stream>>>(a1);
  K2<<<704, 256, 0, stream>>>(a2);
  K3<<<Bb, 64, 0, stream>>>(attlP, pmT, psT, PSpT, attrPM, attrPS, attrPR,
                            laDot, keyDot, gbuf, (const float*)d_in[3],
                            (float*)d_out);
}

// Round 12
// 105.342 us; speedup vs baseline: 1.7778x; 1.0366x over previous
//
#include <hip/hip_runtime.h>

// Problem dims
#define Bb 8
#define Gg 512
#define Kk 64
#define Nn 1024
#define Mm 128
#define KM 8192           // Kk*Mm
#define GPB 16            // g per z-block (r7-proven config)
#define NCH 32            // Gg/GPB partial chunks

struct K1Args {
  const float *z, *hs_grid, *hs_key, *z1w;
  const float *wra_w, *wrh_w, *wla_w, *wlh_w, *kR_w;
  const float *wla_b, *wlh_b, *kR_b, *wra_b, *wrh_b;
  const float *wcl_w, *wcl_b, *wcR_w;
  const float *mapL_w, *mapL_b, *fin_w, *fin_b;
  float *att, *laNum, *laDen, *ra, *Lk, *gbuf;
};

// ===========================================================================
// K1 (1024 threads, r7-proven z-loop):
//  [0,256)   z-pass: att, la partials (NCH=32), DIVIDED ra[b,g,m]
//  [256,320) Lk chain
//  [320]     g-vector block
// gbuf: gv1[0:128) gv2[128:256) gu[256:384) gw1[384:512) gw2[512:640)
//       Cfull[640] fvecL[641:645)
// ===========================================================================
__global__ __launch_bounds__(1024) void K1(K1Args a) {
  __shared__ __align__(16) float smem[10240];   // 40 KB
  const int bid = blockIdx.x;
  const int t = threadIdx.x;

  if (bid < 256) {
    // ---------------- z-pass (verbatim r7 kA structure) ----------------
    float* s_hsgrid = smem;            // 2048
    float* s_rn     = smem + 2048;     // 2 x 2048 (double buffered)
    float* s_rd     = smem + 6144;     // 2 x 2048

    const int b = bid >> 5;
    const int gblk = bid & 31;
    const int lane_m = t & 31;
    const int m4 = lane_m << 2;
    const int kgrp = t >> 5;           // 0..31
    const int wv = t >> 6;             // 0..15

    const float* hgb = a.hs_grid + ((size_t)b * Gg + gblk * GPB) * Mm;
    for (int idx = t; idx < GPB * Mm; idx += 1024) s_hsgrid[idx] = hgb[idx];

    const int ofs0 = (kgrp * 2) * Mm + m4;
    const int ofs1 = ofs0 + Mm;
    // hs_key fragment in registers — constant across the g loop
    const float4 hk0 = *reinterpret_cast<const float4*>(a.hs_key + (size_t)b * KM + ofs0);
    const float4 hk1 = *reinterpret_cast<const float4*>(a.hs_key + (size_t)b * KM + ofs1);

    const float zw0 = a.z1w[m4], zw1 = a.z1w[m4 + 1], zw2 = a.z1w[m4 + 2], zw3 = a.z1w[m4 + 3];

    float la_n[2][4], la_d[2][4];
#pragma unroll
    for (int i = 0; i < 2; ++i)
#pragma unroll
      for (int j = 0; j < 4; ++j) { la_n[i][j] = 0.f; la_d[i][j] = 0.f; }

    const float* zb = a.z + ((size_t)b * Gg + gblk * GPB) * (size_t)KM;
    float4 c0 = *reinterpret_cast<const float4*>(zb + ofs0);
    float4 c1 = *reinterpret_cast<const float4*>(zb + ofs1);

    __syncthreads();   // staging ready

    for (int gl = 0; gl < GPB; ++gl) {
      float4 n0 = c0, n1 = c1;
      if (gl < GPB - 1) {
        n0 = *reinterpret_cast<const float4*>(zb + (size_t)(gl + 1) * KM + ofs0);
        n1 = *reinterpret_cast<const float4*>(zb + (size_t)(gl + 1) * KM + ofs1);
      }
      const int g = gblk * GPB + gl;
      const float4 hg = *reinterpret_cast<const float4*>(s_hsgrid + gl * Mm + m4);
      float rn0 = 0, rn1 = 0, rn2 = 0, rn3 = 0, rd0 = 0, rd1 = 0, rd2 = 0, rd3 = 0;
#pragma unroll
      for (int i = 0; i < 2; ++i) {
        const float4 v = (i == 0) ? c0 : c1;
        const float4 hk = (i == 0) ? hk0 : hk1;
        const int k = kgrp * 2 + i;
        const float e0 = __expf(v.x), e1 = __expf(v.y), e2 = __expf(v.z), e3 = __expf(v.w);
        la_n[i][0] += e0 * hg.x; la_n[i][1] += e1 * hg.y; la_n[i][2] += e2 * hg.z; la_n[i][3] += e3 * hg.w;
        la_d[i][0] += e0;        la_d[i][1] += e1;        la_d[i][2] += e2;        la_d[i][3] += e3;
        rn0 += e0 * hk.x; rn1 += e1 * hk.y; rn2 += e2 * hk.z; rn3 += e3 * hk.w;
        rd0 += e0; rd1 += e1; rd2 += e2; rd3 += e3;
        float ap = v.x * zw0 + v.y * zw1 + v.z * zw2 + v.w * zw3;
        ap += __shfl_xor(ap, 16); ap += __shfl_xor(ap, 8); ap += __shfl_xor(ap, 4);
        ap += __shfl_xor(ap, 2);  ap += __shfl_xor(ap, 1);
        if (lane_m == 0) a.att[((size_t)b * Gg + g) * Kk + k] = ap;
      }
      rn0 += __shfl_xor(rn0, 32); rn1 += __shfl_xor(rn1, 32); rn2 += __shfl_xor(rn2, 32); rn3 += __shfl_xor(rn3, 32);
      rd0 += __shfl_xor(rd0, 32); rd1 += __shfl_xor(rd1, 32); rd2 += __shfl_xor(rd2, 32); rd3 += __shfl_xor(rd3, 32);
      float* rnB = s_rn + (gl & 1) * 2048;
      float* rdB = s_rd + (gl & 1) * 2048;
      if ((t & 63) < 32) {
        *reinterpret_cast<float4*>(rnB + wv * Mm + m4) = make_float4(rn0, rn1, rn2, rn3);
        *reinterpret_cast<float4*>(rdB + wv * Mm + m4) = make_float4(rd0, rd1, rd2, rd3);
      }
      __syncthreads();
      if (t < Mm) {
        float num = 0.f, den = 0.f;
#pragma unroll
        for (int ww = 0; ww < 16; ++ww) { num += rnB[ww * Mm + t]; den += rdB[ww * Mm + t]; }
        a.ra[((size_t)b * Gg + g) * Mm + t] = num / den;
      }
      c0 = n0; c1 = n1;
    }

    const size_t base = ((size_t)(b * NCH + gblk)) * KM;
#pragma unroll
    for (int i = 0; i < 2; ++i) {
      const int k = kgrp * 2 + i;
      *reinterpret_cast<float4*>(a.laNum + base + k * Mm + m4) =
          make_float4(la_n[i][0], la_n[i][1], la_n[i][2], la_n[i][3]);
      *reinterpret_cast<float4*>(a.laDen + base + k * Mm + m4) =
          make_float4(la_d[i][0], la_d[i][1], la_d[i][2], la_d[i][3]);
    }
  } else if (bid < 320) {
    // ---------------- Lk chain: lh = key@wcl.T + bl ; Lk = lh@wcR ----------
    float* s_w  = smem;          // 32 x 132 = 4224
    float* s_lh = smem + 4224;   // 8 x 132
    const int blk = bid - 256;
    const int b = blk >> 3, k8 = blk & 7;
    const int m = t & 127, kq = t >> 7;   // 0..7
    const int k = k8 * 8 + kq;
    float lh = 0.f;
    for (int hc = 0; hc < 4; ++hc) {
      for (int i = t; i < 4096; i += 1024) {
        const int mm = i >> 5, hh = i & 31;
        s_w[hh * 132 + mm] = a.wcl_w[(size_t)mm * Mm + hc * 32 + hh];
      }
      __syncthreads();
      const float* keyb = a.hs_key + ((size_t)b * Kk + k) * Mm + hc * 32;  // wave-uniform
      for (int hh = 0; hh < 32; ++hh) lh += keyb[hh] * s_w[hh * 132 + m];
      __syncthreads();
    }
    s_lh[kq * 132 + m] = lh + a.wcl_b[m];
    __syncthreads();
    float acc = 0.f;
    for (int mm = 0; mm < 128; ++mm)
      acc += s_lh[kq * 132 + mm] * a.wcR_w[(size_t)mm * Mm + m];
    a.Lk[((size_t)b * Kk + k) * Mm + m] = acc;
  } else {
    // ---------------- g-vector block ----------------
    float* s_fvec = smem;        // 260
    float* s_red  = smem + 260;  // 256
    if (t < 260) {
      float f = 0.f;
#pragma unroll
      for (int l = 0; l < 5; ++l) f += a.fin_w[l] * a.mapL_w[l * 260 + t];
      s_fvec[t] = f;
    }
    __syncthreads();
    const int h = t & 127, sel = t >> 7;   // 0..7
    if (sel < 5) {
      const float* W = (sel == 0) ? a.wla_w : (sel == 1) ? a.wlh_w :
                       (sel == 2) ? a.kR_w : (sel == 3) ? a.wra_w : a.wrh_w;
      const float* fv = (sel < 3) ? s_fvec : (s_fvec + 132);
      float g = 0.f;
      for (int mm = 0; mm < 128; ++mm) g += fv[mm] * W[(size_t)mm * Mm + h];
      a.gbuf[sel * 128 + h] = g;
    }
    if (t < 128) {
      s_red[t] = s_fvec[t] * (a.wla_b[t] + a.wlh_b[t] + a.kR_b[t]);
      s_red[128 + t] = s_fvec[132 + t] * (a.wra_b[t] + a.wrh_b[t]);
    }
    __syncthreads();
    if (t == 0) {
      float c1 = 0.f, c2 = 0.f;
      for (int i = 0; i < 128; ++i) { c1 += s_red[i]; c2 += s_red[128 + i]; }
      float C = a.fin_b[0];
#pragma unroll
      for (int l = 0; l < 5; ++l) C += a.fin_w[l] * a.mapL_b[l];
      // sum att_l = G = 512 exactly; sum att_r = K = 64 exactly
      a.gbuf[640] = C + 512.0f * c1 + 64.0f * c2;
#pragma unroll
      for (int e = 0; e < 4; ++e) a.gbuf[641 + e] = s_fvec[128 + e];
    }
  }
}

struct K2Args {
  const float *laNum, *laDen, *hs_key, *att, *ra, *hs_grid, *Lk, *hs_rec;
  const int *mask;
  const float *wRl, *gbuf;
  float *attlP, *attrPM, *attrPS, *attrPR, *pmT, *psT, *PSpT, *laDot, *keyDot;
};

// ===========================================================================
// K2: [0,64) laDot/keyDot | [64,128) att_l partials | [128,192) att_r with
//     inline rdot from divided ra | [192,704) scores tiles -> pm/ps/PSp
// ===========================================================================
__global__ __launch_bounds__(256) void K2(K2Args a) {
  __shared__ __align__(16) float smem[4944];
  const int bid = blockIdx.x;
  const int t = threadIdx.x;

  if (bid < 64) {
    // ---- laDot[b,k] = gv1 . (num/den), keyDot[b,k] = gv2 . key[b,k,:]
    const int b = bid >> 3, k8 = bid & 7;
    const int m = t & 127, kh = t >> 7;
    const float g1 = a.gbuf[m], g2 = a.gbuf[128 + m];
    float* sl = smem;            // 8*132
    float* sk = smem + 1056;     // 8*132
#pragma unroll
    for (int i = 0; i < 4; ++i) {
      const int k = k8 * 8 + kh * 4 + i;
      const float* np = a.laNum + (size_t)b * NCH * KM + (size_t)k * Mm + m;
      const float* dp = a.laDen + (size_t)b * NCH * KM + (size_t)k * Mm + m;
      float num = 0.f, den = 0.f;
#pragma unroll 8
      for (int p = 0; p < NCH; ++p) { num += np[(size_t)p * KM]; den += dp[(size_t)p * KM]; }
      sl[(kh * 4 + i) * 132 + m] = g1 * (num / den);
      sk[(kh * 4 + i) * 132 + m] = g2 * a.hs_key[((size_t)b * Kk + k) * Mm + m];
    }
    __syncthreads();
    const int rid = t >> 5, l32 = t & 31;
    float s1 = sl[rid * 132 + l32] + sl[rid * 132 + l32 + 32] +
               sl[rid * 132 + l32 + 64] + sl[rid * 132 + l32 + 96];
    float s2 = sk[rid * 132 + l32] + sk[rid * 132 + l32 + 32] +
               sk[rid * 132 + l32 + 64] + sk[rid * 132 + l32 + 96];
#pragma unroll
    for (int off = 16; off; off >>= 1) { s1 += __shfl_xor(s1, off); s2 += __shfl_xor(s2, off); }
    if (l32 == 0) {
      a.laDot[b * Kk + k8 * 8 + rid] = s1;
      a.keyDot[b * Kk + k8 * 8 + rid] = s2;
    }
  } else if (bid < 128) {
    // ---- att_l partials ----
    const int blk = bid - 64;
    const int b = blk >> 3, p = blk & 7;
    const int w = t >> 6, lane = t & 63;
    float acc = 0.f;
    for (int j = 0; j < 16; ++j) {
      const int g = p * 64 + w * 16 + j;
      const float av = a.att[((size_t)b * Gg + g) * Kk + lane];
      float mx = av;
      for (int off = 32; off; off >>= 1) mx = fmaxf(mx, __shfl_xor(mx, off));
      const float e = __expf(av - mx);
      float s = e;
      for (int off = 32; off; off >>= 1) s += __shfl_xor(s, off);
      acc += e / s;
    }
    float* sred = smem;
    sred[w * 64 + lane] = acc;
    __syncthreads();
    if (t < 64) a.attlP[(b * 8 + p) * 64 + t] = sred[t] + sred[64 + t] + sred[128 + t] + sred[192 + t];
  } else if (bid < 192) {
    // ---- att_r: inline rdot (from divided ra) + online partials per (b,gc) ----
    const int blk = bid - 128;
    const int b = blk >> 3, gc = blk & 7;
    float* s_gw   = smem;          // 256 (gw1, gw2)
    float* s_rdot = smem + 256;    // 64
    float* sm = smem + 320;        // 256
    float* ss = smem + 576;        // 256
    float* sr = smem + 832;        // 256
    s_gw[t] = a.gbuf[384 + t];
    __syncthreads();
    {
      const int gg = t >> 2, q = t & 3;
      const int g = gc * 64 + gg;
      const float* rp_ = a.ra + ((size_t)b * Gg + g) * Mm + q * 32;
      const float* hp = a.hs_grid + ((size_t)b * Gg + g) * Mm + q * 32;
      float acc = 0.f;
#pragma unroll
      for (int j4 = 0; j4 < 8; ++j4) {
        const float4 rv = *reinterpret_cast<const float4*>(rp_ + j4 * 4);
        const float4 hv = *reinterpret_cast<const float4*>(hp + j4 * 4);
        const int mb = q * 32 + j4 * 4;
        acc += s_gw[mb + 0] * rv.x + s_gw[128 + mb + 0] * hv.x;
        acc += s_gw[mb + 1] * rv.y + s_gw[128 + mb + 1] * hv.y;
        acc += s_gw[mb + 2] * rv.z + s_gw[128 + mb + 2] * hv.z;
        acc += s_gw[mb + 3] * rv.w + s_gw[128 + mb + 3] * hv.w;
      }
      acc += __shfl_xor(acc, 1);
      acc += __shfl_xor(acc, 2);
      if (q == 0) s_rdot[gg] = acc;
    }
    __syncthreads();
    const int k = t & 63, j4 = t >> 6;
    float m_ = -3.0e38f, s_ = 0.f, r_ = 0.f;
    for (int j = 0; j < 16; ++j) {
      const int gg = j4 * 16 + j;
      const float av = a.att[((size_t)b * Gg + gc * 64 + gg) * Kk + k];
      const float rv = s_rdot[gg];
      if (av > m_) {
        const float sc = __expf(m_ - av);
        s_ = s_ * sc + 1.0f; r_ = r_ * sc + rv; m_ = av;
      } else {
        const float e = __expf(av - m_);
        s_ += e; r_ += e * rv;
      }
    }
    sm[j4 * 64 + k] = m_; ss[j4 * 64 + k] = s_; sr[j4 * 64 + k] = r_;
    __syncthreads();
    if (t < 64) {
      float M = sm[t];
      for (int q = 1; q < 4; ++q) M = fmaxf(M, sm[q * 64 + t]);
      float S = 0.f, R = 0.f;
      for (int q = 0; q < 4; ++q) {
        const float e = __expf(sm[q * 64 + t] - M);
        S += ss[q * 64 + t] * e; R += sr[q * 64 + t] * e;
      }
      const int o = (b * 8 + gc) * 64 + t;
      a.attrPM[o] = M; a.attrPS[o] = S; a.attrPR[o] = R;
    }
  } else {
    // ---- scores tile: pm/ps/PSp partials (scores stay in registers) ----
    const int vb = bid - 192;
    const int b = vb >> 6, ntile = vb & 63;
    const int n0 = ntile * 16;
    const int k = t & 63;
    const int hq = __builtin_amdgcn_readfirstlane(t >> 6);
    float* s_acc = smem;          // 4096
    float* s_m   = smem + 4096;   // 256
    float* s_s   = smem + 4352;   // 256
    float* s_p   = smem + 4608;   // 256
    float* s_ru4 = smem + 4864;   // 64
    float* s_ru  = smem + 4928;   // 16
    float rLk[32];
    {
      const float* Lp = a.Lk + ((size_t)b * Kk + k) * Mm + hq * 32;
#pragma unroll
      for (int j = 0; j < 8; ++j) {
        const float4 v = *reinterpret_cast<const float4*>(Lp + j * 4);
        rLk[j * 4 + 0] = v.x; rLk[j * 4 + 1] = v.y;
        rLk[j * 4 + 2] = v.z; rLk[j * 4 + 3] = v.w;
      }
    }
    float acc[16];
    const float* rb = a.hs_rec + ((size_t)b * Nn + n0) * Mm + hq * 32;   // wave-uniform
#pragma unroll
    for (int r = 0; r < 16; ++r) {
      const float* rp = rb + r * Mm;
      float s = 0.f;
#pragma unroll
      for (int j4 = 0; j4 < 8; ++j4) {
        const float4 rv = *reinterpret_cast<const float4*>(rp + j4 * 4);
        s += rv.x * rLk[j4 * 4] + rv.y * rLk[j4 * 4 + 1] +
             rv.z * rLk[j4 * 4 + 2] + rv.w * rLk[j4 * 4 + 3];
      }
      acc[r] = s;
    }
#pragma unroll
    for (int r = 0; r < 16; ++r) s_acc[(hq * 16 + r) * 64 + k] = acc[r];
    if (t < 64) {   // ru[n] = gu . rec[n,:] partials
      const int rt = t >> 2, hc = t & 3;
      const float* rp = a.hs_rec + ((size_t)b * Nn + n0 + rt) * Mm + hc * 32;
      const float* gu = a.gbuf + 256 + hc * 32;
      float s = 0.f;
#pragma unroll
      for (int j = 0; j < 32; ++j) s += gu[j] * rp[j];
      s_ru4[rt * 4 + hc] = s;
    }
    __syncthreads();
    if (t < 16) s_ru[t] = s_ru4[t * 4] + s_ru4[t * 4 + 1] + s_ru4[t * 4 + 2] + s_ru4[t * 4 + 3];
    __syncthreads();
    const float wv = a.wRl[0];
    const bool msk = (a.mask[b * Kk + k] == 0);
    float m = -3.0e38f, ssum = 0.f, psum = 0.f;
    const int hq4 = (t >> 6) * 4;
#pragma unroll
    for (int q = 0; q < 4; ++q) {
      const int r = hq4 + q;
      float v = s_acc[r * 64 + k] + s_acc[(16 + r) * 64 + k] +
                s_acc[(32 + r) * 64 + k] + s_acc[(48 + r) * 64 + k];
      v = msk ? -1e10f : wv * v;
      const float runow = s_ru[r];
      if (v > m) {
        const float sc = __expf(m - v);
        ssum = ssum * sc + 1.0f; psum = psum * sc + runow; m = v;
      } else {
        const float e = __expf(v - m);
        ssum += e; psum += e * runow;
      }
    }
    s_m[(t >> 6) * 64 + k] = m; s_s[(t >> 6) * 64 + k] = ssum; s_p[(t >> 6) * 64 + k] = psum;
    __syncthreads();
    if (t < 64) {
      float M = fmaxf(fmaxf(s_m[t], s_m[64 + t]), fmaxf(s_m[128 + t], s_m[192 + t]));
      float S = 0.f, P = 0.f;
#pragma unroll
      for (int q = 0; q < 4; ++q) {
        const float e = __expf(s_m[q * 64 + t] - M);
        S += s_s[q * 64 + t] * e; P += s_p[q * 64 + t] * e;
      }
      const size_t o = ((size_t)b * 64 + ntile) * 64 + t;
      a.pmT[o] = M; a.psT[o] = S; a.PSpT[o] = P;
    }
  }
}

// ===========================================================================
// K3: per-b finale (8 blocks x 64 threads): scalar assembly
// ===========================================================================
__global__ __launch_bounds__(64) void K3(
    const float* __restrict__ attlP, const float* __restrict__ pmT,
    const float* __restrict__ psT, const float* __restrict__ PSpT,
    const float* __restrict__ attrPM, const float* __restrict__ attrPS,
    const float* __restrict__ attrPR,
    const float* __restrict__ laDot, const float* __restrict__ keyDot,
    const float* __restrict__ gbuf, const float* __restrict__ lig_rep,
    float* __restrict__ out)
{
  const int b = blockIdx.x, t = threadIdx.x;   // t = k
  float attl = 0.f;
#pragma unroll
  for (int p = 0; p < 8; ++p) attl += attlP[(b * 8 + p) * 64 + t];
  float M = -3.0e38f, S = 0.f, P = 0.f;
  for (int nt = 0; nt < 64; ++nt) {
    const size_t o = ((size_t)b * 64 + nt) * 64 + t;
    const float pm_ = pmT[o], ps_ = psT[o], pp = PSpT[o];
    if (pm_ > M) {
      const float sc = __expf(M - pm_);
      S = S * sc + ps_; P = P * sc + pp; M = pm_;
    } else {
      const float e = __expf(pm_ - M);
      S += ps_ * e; P += pp * e;
    }
  }
  float Mr = -3.0e38f, Sr = 0.f, Rr = 0.f;
  for (int p = 0; p < 8; ++p) {
    const int o = (b * 8 + p) * 64 + t;
    const float pm_ = attrPM[o], ps_ = attrPS[o], pr_ = attrPR[o];
    if (pm_ > Mr) {
      const float sc = __expf(Mr - pm_);
      Sr = Sr * sc + ps_; Rr = Rr * sc + pr_; Mr = pm_;
    } else {
      const float e = __expf(pm_ - Mr);
      Sr += ps_ * e; Rr += pr_ * e;
    }
  }
  float val = attl * (laDot[b * 64 + t] + keyDot[b * 64 + t] + P / S) + Rr / Sr;
#pragma unroll
  for (int off = 32; off; off >>= 1) val += __shfl_xor(val, off);
  if (t == 0) {
    float o = val + gbuf[640];
#pragma unroll
    for (int e = 0; e < 4; ++e) o += gbuf[641 + e] * lig_rep[b * 4 + e];
    out[b] = o;
  }
}

// ---------------------------------------------------------------------------
extern "C" void kernel_launch(void* const* d_in, const int* in_sizes, int n_in,
                              void* d_out, int out_size, void* d_ws, size_t ws_size,
                              hipStream_t stream) {
  float* w = (float*)d_ws;
  float* gbuf  = w;                       // 1024
  float* att   = gbuf + 1024;             // 262144
  float* laNum = att + Bb * Gg * Kk;      // 2097152
  float* laDen = laNum + Bb * NCH * KM;   // 2097152
  float* ra    = laDen + Bb * NCH * KM;   // 524288
  float* Lk    = ra + Bb * Gg * Mm;       // 65536
  float* attlP = Lk + Bb * Kk * Mm;       // 4096
  float* pmT   = attlP + Bb * 8 * 64;     // 32768
  float* psT   = pmT + Bb * 64 * 64;      // 32768
  float* PSpT  = psT + Bb * 64 * 64;      // 32768
  float* laDot = PSpT + Bb * 64 * 64;     // 512
  float* keyDot = laDot + Bb * Kk;        // 512
  float* attrPM = keyDot + Bb * Kk;       // 4096
  float* attrPS = attrPM + Bb * 8 * 64;   // 4096
  float* attrPR = attrPS + Bb * 8 * 64;   // 4096

  K1Args a1;
  a1.z = (const float*)d_in[0];
  a1.hs_grid = (const float*)d_in[1];
  a1.hs_key = (const float*)d_in[2];
  a1.z1w = (const float*)d_in[15];
  a1.wra_w = (const float*)d_in[7];  a1.wra_b = (const float*)d_in[8];
  a1.wrh_w = (const float*)d_in[9];  a1.wrh_b = (const float*)d_in[10];
  a1.wla_w = (const float*)d_in[11]; a1.wla_b = (const float*)d_in[12];
  a1.wlh_w = (const float*)d_in[13]; a1.wlh_b = (const float*)d_in[14];
  a1.wcl_w = (const float*)d_in[19]; a1.wcl_b = (const float*)d_in[20];
  a1.wcR_w = (const float*)d_in[17];
  a1.kR_w  = (const float*)d_in[21]; a1.kR_b = (const float*)d_in[22];
  a1.mapL_w = (const float*)d_in[23]; a1.mapL_b = (const float*)d_in[24];
  a1.fin_w = (const float*)d_in[25]; a1.fin_b = (const float*)d_in[26];
  a1.att = att; a1.laNum = laNum; a1.laDen = laDen;
  a1.ra = ra; a1.Lk = Lk; a1.gbuf = gbuf;

  K2Args a2;
  a2.laNum = laNum; a2.laDen = laDen;
  a2.hs_key = (const float*)d_in[2];
  a2.att = att; a2.ra = ra;
  a2.hs_grid = (const float*)d_in[1];
  a2.Lk = Lk;
  a2.hs_rec = (const float*)d_in[4];
  a2.mask = (const int*)d_in[6];
  a2.wRl = (const float*)d_in[5];
  a2.gbuf = gbuf;
  a2.attlP = attlP;
  a2.attrPM = attrPM; a2.attrPS = attrPS; a2.attrPR = attrPR;
  a2.pmT = pmT; a2.psT = psT; a2.PSpT = PSpT;
  a2.laDot = laDot; a2.keyDot = keyDot;

  K1<<<321, 1024, 0, stream>>>(a1);
  K2<<<704, 256, 0, stream>>>(a2);
  K3<<<Bb, 64, 0, stream>>>(attlP, pmT, psT, PSpT, attrPM, attrPS, attrPR,
                            laDot, keyDot, gbuf, (const float*)d_in[3],
                            (float*)d_out);
}